// Round 3
// baseline (1039.054 us; speedup 1.0000x reference)
//
#include <hip/hip_runtime.h>
#include <math.h>

#define B_ 4
#define L_ 2048
#define D_ 1024
#define H_ 16
#define HD_ 64
#define K_ 24
#define MLP_ 4096

typedef unsigned short u16;
typedef short s16x8 __attribute__((ext_vector_type(8)));
typedef float fx4 __attribute__((ext_vector_type(4)));
typedef _Float16 h2 __attribute__((ext_vector_type(2)));

__device__ __forceinline__ u16 f2bf(float f) {
    unsigned u = __float_as_uint(f);
    unsigned r = (u + 0x7fff + ((u >> 16) & 1)) >> 16;
    return (u16)r;
}

__device__ __forceinline__ float gelu_t(float x) {
    float u = 0.7978845608028654f * (x + 0.044715f * x * x * x);
    return x / (1.f + __expf(-2.f * u));
}

__device__ __forceinline__ void gload_lds16(const void* g, void* l) {
    __builtin_amdgcn_global_load_lds(
        (const __attribute__((address_space(1))) unsigned int*)g,
        (__attribute__((address_space(3))) unsigned int*)l, 16, 0, 0);
}

// ---------------------------------------------------------------------------
// filters[l,d] = sum_k eig_vecs[l,k] * eig_vals[k]^0.25 * w_filters[k,d]
// ---------------------------------------------------------------------------
__global__ void filters_kernel(const float* __restrict__ eig_vals,
                               const float* __restrict__ eig_vecs,
                               const float* __restrict__ w_filters,
                               float* __restrict__ out) {
    int l = blockIdx.x;
    int d = blockIdx.y * 256 + threadIdx.x;
    __shared__ float r[K_];
    if (threadIdx.x < K_) {
        float ev = eig_vals[threadIdx.x];
        r[threadIdx.x] = eig_vecs[l * K_ + threadIdx.x] * powf(ev, 0.25f);
    }
    __syncthreads();
    float acc = 0.f;
#pragma unroll
    for (int k = 0; k < K_; k++) acc += r[k] * w_filters[k * D_ + d];
    out[(size_t)l * D_ + d] = acc;
}

// ---------------------------------------------------------------------------
__global__ __launch_bounds__(256) void cast_bf16(const float* __restrict__ in,
                                                 u16* __restrict__ out) {
    int i = blockIdx.x * 256 + threadIdx.x;
    float4 v = ((const float4*)in)[i];
    ushort4 o;
    o.x = f2bf(v.x); o.y = f2bf(v.y); o.z = f2bf(v.z); o.w = f2bf(v.w);
    ((ushort4*)out)[i] = o;
}

// ---------------------------------------------------------------------------
// fp32 [R][C] -> bf16 [C][R] transpose-cast (32x32 LDS tile)
// ---------------------------------------------------------------------------
__global__ __launch_bounds__(256) void cast_T(const float* __restrict__ in,
                                              u16* __restrict__ out, int R, int C) {
    __shared__ float t[32][33];
    int c0 = blockIdx.x * 32, r0 = blockIdx.y * 32;
    int tx = threadIdx.x & 31, ty = threadIdx.x >> 5;
#pragma unroll
    for (int p = 0; p < 4; p++)
        t[ty + p * 8][tx] = in[(size_t)(r0 + ty + p * 8) * C + c0 + tx];
    __syncthreads();
#pragma unroll
    for (int p = 0; p < 4; p++)
        out[(size_t)(c0 + ty + p * 8) * R + r0 + tx] = f2bf(t[tx][ty + p * 8]);
}

// ---------------------------------------------------------------------------
// bf16 MFMA GEMM: out = act(alpha * A @ Bt^T + bias) + resid
// qcols: columns < qcols get alpha*0.125 (fused-QKV Q-scale)
// ---------------------------------------------------------------------------
__global__ __launch_bounds__(256) void gemm_bf16(
    const u16* __restrict__ A, const u16* __restrict__ Bt,
    float* __restrict__ C, u16* __restrict__ Cb,
    int M, int N, int K, float alpha,
    const float* __restrict__ bias, const float* __restrict__ resid, int act,
    int qcols) {
    __shared__ u16 As[4][128][8];
    __shared__ u16 Bs[4][128][8];
    int tid = threadIdx.x;
    int wid = tid >> 6, lane = tid & 63;
    int bm = blockIdx.y * 128, bn = blockIdx.x * 128;
    int wm = (wid >> 1) * 64, wn = (wid & 1) * 64;
    int q = lane >> 4, r = lane & 15;

    const u16* gA0 = A + (size_t)(bm + lane) * K + wid * 8;
    const u16* gA1 = gA0 + (size_t)64 * K;
    const u16* gB0 = Bt + (size_t)(bn + lane) * K + wid * 8;
    const u16* gB1 = gB0 + (size_t)64 * K;
    u16* lA0 = &As[wid][0][0];
    u16* lA1 = &As[wid][64][0];
    u16* lB0 = &Bs[wid][0][0];
    u16* lB1 = &Bs[wid][64][0];
    const u16* pa = &As[q][wm + r][0];
    const u16* pb = &Bs[q][wn + r][0];

    fx4 acc[4][4];
#pragma unroll
    for (int i = 0; i < 4; i++)
#pragma unroll
        for (int j = 0; j < 4; j++) acc[i][j] = (fx4){0.f, 0.f, 0.f, 0.f};

    for (int k0 = 0; k0 < K; k0 += 32) {
        if (k0) __syncthreads();
        gload_lds16(gA0 + k0, lA0);
        gload_lds16(gA1 + k0, lA1);
        gload_lds16(gB0 + k0, lB0);
        gload_lds16(gB1 + k0, lB1);
        __syncthreads();
        s16x8 a[4], b[4];
#pragma unroll
        for (int i = 0; i < 4; i++) a[i] = *(const s16x8*)(pa + i * 128);
#pragma unroll
        for (int j = 0; j < 4; j++) b[j] = *(const s16x8*)(pb + j * 128);
#pragma unroll
        for (int i = 0; i < 4; i++)
#pragma unroll
            for (int j = 0; j < 4; j++)
                acc[i][j] = __builtin_amdgcn_mfma_f32_16x16x32_bf16(
                    a[i], b[j], acc[i][j], 0, 0, 0);
    }

#pragma unroll
    for (int i = 0; i < 4; i++) {
        int row0 = bm + wm + i * 16 + q * 4;
#pragma unroll
        for (int j = 0; j < 4; j++) {
            int col = bn + wn + j * 16 + r;
            float a2 = (col < qcols) ? alpha * 0.125f : alpha;
            float bv = bias ? bias[col] : 0.f;
#pragma unroll
            for (int reg = 0; reg < 4; reg++) {
                float v = a2 * acc[i][j][reg] + bv;
                if (act) v = gelu_t(v);
                size_t idx = (size_t)(row0 + reg) * N + col;
                if (resid) v += resid[idx];
                if (C) C[idx] = v;
                else Cb[idx] = f2bf(v);
            }
        }
    }
}

// ---------------------------------------------------------------------------
// Causal per-channel conv: out[b,l,d] = sum_{t=0..l} F[t,d]*XI[b,l-t,d]
// Balanced pairing (tiles i & 31-i). f16 LDS tiles + v_dot2_f32_f16.
// v3: register-pipelined staging (T14): next tile's 48 global loads are
//     issued right after the compute-entry barrier, so L2/HBM latency hides
//     under the ~1500-cycle fdot2 phase instead of serializing between
//     barriers. cvt+LDS-write happens at the top of the next iteration.
// ---------------------------------------------------------------------------
__global__ __launch_bounds__(256) void conv_k(const float* __restrict__ F,
                                              const float* __restrict__ XI,
                                              float* __restrict__ OUT) {
    int d0 = blockIdx.y * 64, b = blockIdx.z;
    __shared__ u16 xs[64][132];
    __shared__ u16 ftr[64][68];
    int tid = threadIdx.x;
    int dd = tid & 63;
    int jg = tid >> 6;
    int L0 = jg * 16;
    const float* xib = XI + (size_t)b * L_ * D_;
    const float* fcol = F + d0 + dd;
    const float* xcol = xib + d0 + dd;

#pragma unroll 1
    for (int half = 0; half < 2; half++) {
        int lt = half ? (31 - blockIdx.x) : blockIdx.x;
        int l0 = lt * 64;
        float acc[16];
#pragma unroll
        for (int i = 0; i < 16; i++) acc[i] = 0.f;

        float fpre[16], xpre[32];
        // prologue: load t0=0 tile into regs
        {
            int jb = l0 - 63;
#pragma unroll
            for (int mm = 0; mm < 2; mm++) {
                int base = 8 * (jg + 4 * mm);
#pragma unroll
                for (int k = 0; k < 8; k++)
                    fpre[mm * 8 + k] = fcol[(size_t)(base + k) * D_];
            }
#pragma unroll
            for (int mm = 0; mm < 4; mm++) {
                int c0 = 8 * (jg + 4 * mm);
#pragma unroll
                for (int k = 0; k < 8; k++) {
                    int j = jb + c0 + k;
                    xpre[mm * 8 + k] = (j >= 0 && j < L_)
                        ? xcol[(size_t)j * D_] : 0.f;
                }
            }
        }

        for (int t0 = 0; t0 <= l0; t0 += 64) {
            // write staged regs -> LDS (f16, reversed filter)
#pragma unroll
            for (int mm = 0; mm < 2; mm++) {
                int base = 8 * (jg + 4 * mm);
                const float* v = &fpre[mm * 8];
                unsigned u0 = __builtin_bit_cast(unsigned, __builtin_amdgcn_cvt_pkrtz(v[7], v[6]));
                unsigned u1 = __builtin_bit_cast(unsigned, __builtin_amdgcn_cvt_pkrtz(v[5], v[4]));
                unsigned u2 = __builtin_bit_cast(unsigned, __builtin_amdgcn_cvt_pkrtz(v[3], v[2]));
                unsigned u3 = __builtin_bit_cast(unsigned, __builtin_amdgcn_cvt_pkrtz(v[1], v[0]));
                *(uint2*)&ftr[dd][56 - base] = make_uint2(u0, u1);
                *(uint2*)&ftr[dd][60 - base] = make_uint2(u2, u3);
            }
#pragma unroll
            for (int mm = 0; mm < 4; mm++) {
                int c0 = 8 * (jg + 4 * mm);
                const float* x = &xpre[mm * 8];
                unsigned u0 = __builtin_bit_cast(unsigned, __builtin_amdgcn_cvt_pkrtz(x[0], x[1]));
                unsigned u1 = __builtin_bit_cast(unsigned, __builtin_amdgcn_cvt_pkrtz(x[2], x[3]));
                unsigned u2 = __builtin_bit_cast(unsigned, __builtin_amdgcn_cvt_pkrtz(x[4], x[5]));
                unsigned u3 = __builtin_bit_cast(unsigned, __builtin_amdgcn_cvt_pkrtz(x[6], x[7]));
                *(uint2*)&xs[dd][c0] = make_uint2(u0, u1);
                *(uint2*)&xs[dd][c0 + 4] = make_uint2(u2, u3);
            }
            __syncthreads();

            // prefetch next tile's globals (in flight across the fdot2 phase)
            if (t0 + 64 <= l0) {
                int t1 = t0 + 64;
                int jb = l0 - t1 - 63;
#pragma unroll
                for (int mm = 0; mm < 2; mm++) {
                    int base = 8 * (jg + 4 * mm);
#pragma unroll
                    for (int k = 0; k < 8; k++)
                        fpre[mm * 8 + k] = fcol[(size_t)(t1 + base + k) * D_];
                }
#pragma unroll
                for (int mm = 0; mm < 4; mm++) {
                    int c0 = 8 * (jg + 4 * mm);
#pragma unroll
                    for (int k = 0; k < 8; k++) {
                        int j = jb + c0 + k;
                        xpre[mm * 8 + k] = (j >= 0 && j < L_)
                            ? xcol[(size_t)j * D_] : 0.f;
                    }
                }
            }

            // init window: E[j]=(W[2j],W[2j+1]) j=0..7; O[j]=(W[2j+1],W[2j+2])
            unsigned E[10], O[10];
            {
                uint2 w0 = *(const uint2*)&xs[dd][L0];
                uint2 w1 = *(const uint2*)&xs[dd][L0 + 4];
                uint2 w2 = *(const uint2*)&xs[dd][L0 + 8];
                uint2 w3 = *(const uint2*)&xs[dd][L0 + 12];
                E[0] = w0.x; E[1] = w0.y; E[2] = w1.x; E[3] = w1.y;
                E[4] = w2.x; E[5] = w2.y; E[6] = w3.x; E[7] = w3.y;
#pragma unroll
                for (int j = 0; j < 7; j++)
                    O[j] = __builtin_amdgcn_alignbit(E[j + 1], E[j], 16);
            }
#pragma unroll
            for (int s = 0; s < 16; s++) {
                const int h = (2 * s) % 10;
                uint2 nx = *(const uint2*)&xs[dd][L0 + 16 + 4 * s];
                E[(h + 8) % 10] = nx.x;
                E[(h + 9) % 10] = nx.y;
                O[(h + 7) % 10] = __builtin_amdgcn_alignbit(E[(h + 8) % 10], E[(h + 7) % 10], 16);
                O[(h + 8) % 10] = __builtin_amdgcn_alignbit(E[(h + 9) % 10], E[(h + 8) % 10], 16);
                uint2 fr = *(const uint2*)&ftr[dd][4 * s];
                h2 f01 = __builtin_bit_cast(h2, fr.x);
                h2 f23 = __builtin_bit_cast(h2, fr.y);
#pragma unroll
                for (int i = 0; i < 16; i += 2) {
                    const int p = (h + i / 2) % 10;
                    const int p1 = (h + i / 2 + 1) % 10;
                    acc[i] = __builtin_amdgcn_fdot2(f01, __builtin_bit_cast(h2, E[p]), acc[i], false);
                    acc[i] = __builtin_amdgcn_fdot2(f23, __builtin_bit_cast(h2, E[p1]), acc[i], false);
                    acc[i + 1] = __builtin_amdgcn_fdot2(f01, __builtin_bit_cast(h2, O[p]), acc[i + 1], false);
                    acc[i + 1] = __builtin_amdgcn_fdot2(f23, __builtin_bit_cast(h2, O[p1]), acc[i + 1], false);
                }
            }
            __syncthreads();
        }
#pragma unroll
        for (int i = 0; i < 16; i++)
            OUT[((size_t)b * L_ + l0 + L0 + i) * D_ + d0 + dd] = acc[i];
    }
}

// ---------------------------------------------------------------------------
// LayerNorm -> bf16 out (row = 1024), eps 1e-6
// ---------------------------------------------------------------------------
__global__ __launch_bounds__(256) void layernorm_bf16(const float* __restrict__ x,
                                                      const float* __restrict__ scale,
                                                      const float* __restrict__ bias,
                                                      u16* __restrict__ y) {
    size_t row = blockIdx.x;
    int tid = threadIdx.x;
    const float4 v = *(const float4*)&x[row * D_ + tid * 4];
    float s = v.x + v.y + v.z + v.w;
    float q = v.x * v.x + v.y * v.y + v.z * v.z + v.w * v.w;
#pragma unroll
    for (int off = 32; off >= 1; off >>= 1) {
        s += __shfl_xor(s, off, 64);
        q += __shfl_xor(q, off, 64);
    }
    __shared__ float ss[4], sq[4];
    int w = tid >> 6;
    if ((tid & 63) == 0) { ss[w] = s; sq[w] = q; }
    __syncthreads();
    s = ss[0] + ss[1] + ss[2] + ss[3];
    q = sq[0] + sq[1] + sq[2] + sq[3];
    float mean = s * (1.f / D_);
    float var = q * (1.f / D_) - mean * mean;
    float r = rsqrtf(var + 1e-6f);
    const float4 sc = *(const float4*)&scale[tid * 4];
    const float4 bi = *(const float4*)&bias[tid * 4];
    ushort4 o;
    o.x = f2bf((v.x - mean) * r * sc.x + bi.x);
    o.y = f2bf((v.y - mean) * r * sc.y + bi.y);
    o.z = f2bf((v.z - mean) * r * sc.z + bi.z);
    o.w = f2bf((v.w - mean) * r * sc.w + bi.w);
    *(ushort4*)&y[row * D_ + tid * 4] = o;
}

// ---------------------------------------------------------------------------
// MFMA flash attention, TQ=128. Q,K,V are column slices of the fused
// [B*L, 3072] bf16 QKV buffer (stride 3072); Q pre-scaled. Out bf16 [M,1024].
// no-max softmax (scores bounded) + K/V register prefetch.
// ---------------------------------------------------------------------------
__global__ __launch_bounds__(256) void attn_mfma(const u16* __restrict__ Qg,
                                                 const u16* __restrict__ Kg,
                                                 const u16* __restrict__ Vg,
                                                 u16* __restrict__ Og) {
    const int QSTR = 3072;
    int q0 = blockIdx.x * 128;
    int b = blockIdx.y >> 4, h = blockIdx.y & 15;
    __shared__ __align__(16) u16 qs[128 * 72];
    __shared__ __align__(16) u16 ks[64 * 72];
    __shared__ __align__(16) u16 vt[64 * 72];   // V^T: [hd][s]
    int tid = threadIdx.x;
    int w = tid >> 6, lane = tid & 63;
    int quad = lane >> 4, l15 = lane & 15;
    const size_t base = (size_t)b * L_ * QSTR + h * HD_;

    // stage Q tile (once)
#pragma unroll
    for (int i = tid; i < 128 * 8; i += 256) {
        int r = i >> 3, c = i & 7;
        *(uint4*)&qs[r * 72 + c * 8] =
            *(const uint4*)&Qg[base + (size_t)(q0 + r) * QSTR + c * 8];
    }
    __syncthreads();
    s16x8 aq[2][2];
#pragma unroll
    for (int mi = 0; mi < 2; mi++)
#pragma unroll
        for (int kb = 0; kb < 2; kb++)
            aq[mi][kb] = *(const s16x8*)&qs[(w * 32 + mi * 16 + l15) * 72 + kb * 32 + quad * 8];

    float rsacc[2][4];
    fx4 o[2][4];
#pragma unroll
    for (int mi = 0; mi < 2; mi++)
#pragma unroll
        for (int i = 0; i < 4; i++) {
            rsacc[mi][i] = 0.f;
            o[mi][i] = (fx4){0.f, 0.f, 0.f, 0.f};
        }
    u16* psw = qs + w * 32 * 72;   // wave-private (rows this wave hoisted)

    // K/V prefetch pointers (each thread stages 2 uint4 of K, 2 uint4 of V)
    int kr0 = tid >> 3, kc = tid & 7;
    const u16* kg0 = Kg + base + (size_t)kr0 * QSTR + kc * 8;
    const u16* kg1 = kg0 + (size_t)32 * QSTR;
    const u16* vg = Vg + base + (size_t)lane * QSTR + w * 8;
    uint4 kp0 = *(const uint4*)kg0;
    uint4 kp1 = *(const uint4*)kg1;
    uint4 vp0 = *(const uint4*)vg;
    uint4 vp1 = *(const uint4*)(vg + 32);

    for (int s0 = 0; s0 < L_; s0 += 64) {
        __syncthreads();   // prior tile's LDS reads complete
        *(uint4*)&ks[kr0 * 72 + kc * 8] = kp0;
        *(uint4*)&ks[(kr0 + 32) * 72 + kc * 8] = kp1;
        {
            u16 t0[8], t1[8];
            *(uint4*)t0 = vp0;
            *(uint4*)t1 = vp1;
#pragma unroll
            for (int j = 0; j < 8; j++) vt[(w * 8 + j) * 72 + lane] = t0[j];
#pragma unroll
            for (int j = 0; j < 8; j++) vt[(w * 8 + 32 + j) * 72 + lane] = t1[j];
        }
        if (s0 + 64 < L_) {
            size_t off = (size_t)(s0 + 64) * QSTR;
            kp0 = *(const uint4*)(kg0 + off);
            kp1 = *(const uint4*)(kg1 + off);
            vp0 = *(const uint4*)(vg + off);
            vp1 = *(const uint4*)(vg + off + 32);
        }
        __syncthreads();

        // S = Q K^T : per-wave 32q x 64s
        fx4 sv[2][4];
#pragma unroll
        for (int mi = 0; mi < 2; mi++)
#pragma unroll
            for (int nt = 0; nt < 4; nt++) sv[mi][nt] = (fx4){0.f, 0.f, 0.f, 0.f};
#pragma unroll
        for (int kb = 0; kb < 2; kb++)
#pragma unroll
            for (int nt = 0; nt < 4; nt++) {
                s16x8 bk = *(const s16x8*)&ks[(nt * 16 + l15) * 72 + kb * 32 + quad * 8];
#pragma unroll
                for (int mi = 0; mi < 2; mi++)
                    sv[mi][nt] = __builtin_amdgcn_mfma_f32_16x16x32_bf16(
                        aq[mi][kb], bk, sv[mi][nt], 0, 0, 0);
            }

        // linear softmax accumulation (no max subtraction; scores bounded)
#pragma unroll
        for (int mi = 0; mi < 2; mi++)
#pragma unroll
            for (int nt = 0; nt < 4; nt++)
#pragma unroll
                for (int reg = 0; reg < 4; reg++) {
                    float p = __expf(sv[mi][nt][reg]);
                    rsacc[mi][reg] += p;
                    psw[(mi * 16 + quad * 4 + reg) * 72 + nt * 16 + l15] = f2bf(p);
                }

        // PV: O += P V
#pragma unroll
        for (int kb = 0; kb < 2; kb++) {
            s16x8 ap[2];
#pragma unroll
            for (int mi = 0; mi < 2; mi++)
                ap[mi] = *(const s16x8*)&psw[(mi * 16 + l15) * 72 + kb * 32 + quad * 8];
#pragma unroll
            for (int nt = 0; nt < 4; nt++) {
                s16x8 bv = *(const s16x8*)&vt[(nt * 16 + l15) * 72 + kb * 32 + quad * 8];
#pragma unroll
                for (int mi = 0; mi < 2; mi++)
                    o[mi][nt] = __builtin_amdgcn_mfma_f32_16x16x32_bf16(
                        ap[mi], bv, o[mi][nt], 0, 0, 0);
            }
        }
    }
    // epilogue: reduce row-sums across the 16 s-lanes, then O / lsum -> bf16
    float lsum[2][4];
#pragma unroll
    for (int mi = 0; mi < 2; mi++)
#pragma unroll
        for (int reg = 0; reg < 4; reg++) {
            float r = rsacc[mi][reg];
#pragma unroll
            for (int off = 8; off >= 1; off >>= 1)
                r += __shfl_xor(r, off, 16);
            lsum[mi][reg] = r;
        }
    const size_t baseo = (size_t)b * L_ * 1024 + h * HD_;
#pragma unroll
    for (int mi = 0; mi < 2; mi++)
#pragma unroll
        for (int reg = 0; reg < 4; reg++) {
            float inv = 1.f / lsum[mi][reg];
            size_t row = baseo +
                (size_t)(q0 + w * 32 + mi * 16 + quad * 4 + reg) * 1024;
#pragma unroll
            for (int nt = 0; nt < 4; nt++)
                Og[row + nt * 16 + l15] = f2bf(o[mi][nt][reg] * inv);
        }
}

// ---------------------------------------------------------------------------
extern "C" void kernel_launch(void* const* d_in, const int* in_sizes, int n_in,
                              void* d_out, int out_size, void* d_ws, size_t ws_size,
                              hipStream_t stream) {
    const float* inputs   = (const float*)d_in[0];
    const float* eig_vals = (const float*)d_in[1];
    const float* eig_vecs = (const float*)d_in[2];
    const float* w_filt   = (const float*)d_in[3];
    const float* w_inp    = (const float*)d_in[4];
    const float* ln1_s    = (const float*)d_in[5];
    const float* ln1_b    = (const float*)d_in[6];
    const float* wq       = (const float*)d_in[7];
    const float* wk       = (const float*)d_in[8];
    const float* wv       = (const float*)d_in[9];
    const float* wo       = (const float*)d_in[10];
    const float* ln2_s    = (const float*)d_in[11];
    const float* ln2_b    = (const float*)d_in[12];
    const float* w1       = (const float*)d_in[13];
    const float* b1       = (const float*)d_in[14];
    const float* w2       = (const float*)d_in[15];
    const float* b2       = (const float*)d_in[16];
    float* out = (float*)d_out;
    char* ws = (char*)d_ws;
    const size_t MB = 1u << 20;
    // Region plan (peak 192MB):
    //   0-16  : INb bf16                 [dead after XI gemm]
    //  16-42  : weights: WIt@16, WQKVt@18(6MB), WOt@24, W1t@26, W2t@34
    //  48-80  : XI fp32                  [dead after conv]
    //  48-112 : HID bf16 (MLP phase; XI+STU dead by then)
    //  80-112 : STU fp32                 [dead after WO gemm]
    // 112-128 : XN bf16                  [dead after QKV gemm]
    // 128-176 : QKV bf16 fused [M,3072]  [dead after attn]
    // 128-160 : Xb fp32 (after attn)
    // 160-176 : YN bf16 (after WO gemm)
    // 176-184 : Fv fp32                  [dead after conv]
    // 176-192 : Ab bf16 (after attn)     [dead after WO gemm]
    u16*   INb   = (u16*)(ws + 0 * MB);
    u16*   WIt   = (u16*)(ws + 16 * MB);
    u16*   WQKVt = (u16*)(ws + 18 * MB);
    u16*   WOt   = (u16*)(ws + 24 * MB);
    u16*   W1t   = (u16*)(ws + 26 * MB);
    u16*   W2t   = (u16*)(ws + 34 * MB);
    float* XI    = (float*)(ws + 48 * MB);
    u16*   HID   = (u16*)(ws + 48 * MB);
    float* STU   = (float*)(ws + 80 * MB);
    u16*   XN    = (u16*)(ws + 112 * MB);
    u16*   QKV   = (u16*)(ws + 128 * MB);
    float* Xb    = (float*)(ws + 128 * MB);
    u16*   YN    = (u16*)(ws + 160 * MB);
    float* Fv    = (float*)(ws + 176 * MB);
    u16*   Ab    = (u16*)(ws + 176 * MB);

    const int M = B_ * L_;

    cast_bf16<<<(M * D_ / 4 + 255) / 256, 256, 0, stream>>>(inputs, INb);
    cast_T<<<dim3(D_ / 32, D_ / 32), 256, 0, stream>>>(w_inp, WIt, D_, D_);
    cast_T<<<dim3(D_ / 32, D_ / 32), 256, 0, stream>>>(wq, WQKVt + 0 * D_ * D_, D_, D_);
    cast_T<<<dim3(D_ / 32, D_ / 32), 256, 0, stream>>>(wk, WQKVt + 1 * D_ * D_, D_, D_);
    cast_T<<<dim3(D_ / 32, D_ / 32), 256, 0, stream>>>(wv, WQKVt + 2 * D_ * D_, D_, D_);
    cast_T<<<dim3(D_ / 32, D_ / 32), 256, 0, stream>>>(wo, WOt, D_, D_);
    cast_T<<<dim3(MLP_ / 32, D_ / 32), 256, 0, stream>>>(w1, W1t, D_, MLP_);
    cast_T<<<dim3(D_ / 32, MLP_ / 32), 256, 0, stream>>>(w2, W2t, MLP_, D_);

    filters_kernel<<<dim3(L_, D_ / 256), 256, 0, stream>>>(eig_vals, eig_vecs, w_filt, Fv);

    gemm_bf16<<<dim3(D_ / 128, M / 128), 256, 0, stream>>>(
        INb, WIt, XI, nullptr, M, D_, D_, 1.f, nullptr, nullptr, 0, 0);
    conv_k<<<dim3(16, D_ / 64, B_), 256, 0, stream>>>(Fv, XI, STU);
    layernorm_bf16<<<M, 256, 0, stream>>>(STU, ln1_s, ln1_b, XN);
    // fused QKV (cols<1024 get the 1/sqrt(hd) Q-scale)
    gemm_bf16<<<dim3(3 * D_ / 128, M / 128), 256, 0, stream>>>(
        XN, WQKVt, nullptr, QKV, M, 3 * D_, D_, 1.f, nullptr, nullptr, 0, D_);
    attn_mfma<<<dim3(L_ / 128, B_ * H_), 256, 0, stream>>>(
        QKV, QKV + D_, QKV + 2 * D_, Ab);
    gemm_bf16<<<dim3(D_ / 128, M / 128), 256, 0, stream>>>(
        Ab, WOt, Xb, nullptr, M, D_, D_, 1.f, nullptr, STU, 0, 0);
    layernorm_bf16<<<M, 256, 0, stream>>>(Xb, ln2_s, ln2_b, YN);
    gemm_bf16<<<dim3(MLP_ / 128, M / 128), 256, 0, stream>>>(
        YN, W1t, nullptr, HID, M, MLP_, D_, 1.f, b1, nullptr, 1, 0);
    gemm_bf16<<<dim3(D_ / 128, M / 128), 256, 0, stream>>>(
        HID, W2t, out, nullptr, M, D_, MLP_, 1.f, b2, Xb, 0, 0);
}

// Round 4
// 1014.465 us; speedup vs baseline: 1.0242x; 1.0242x over previous
//
#include <hip/hip_runtime.h>
#include <math.h>

#define B_ 4
#define L_ 2048
#define D_ 1024
#define H_ 16
#define HD_ 64
#define K_ 24
#define MLP_ 4096

typedef unsigned short u16;
typedef short s16x8 __attribute__((ext_vector_type(8)));
typedef float fx4 __attribute__((ext_vector_type(4)));
typedef _Float16 h2 __attribute__((ext_vector_type(2)));

__device__ __forceinline__ u16 f2bf(float f) {
    unsigned u = __float_as_uint(f);
    unsigned r = (u + 0x7fff + ((u >> 16) & 1)) >> 16;
    return (u16)r;
}

__device__ __forceinline__ u16 f2h(float f) {
    _Float16 hv = (_Float16)f;
    return __builtin_bit_cast(u16, hv);
}

__device__ __forceinline__ float gelu_t(float x) {
    float u = 0.7978845608028654f * (x + 0.044715f * x * x * x);
    return x / (1.f + __expf(-2.f * u));
}

__device__ __forceinline__ void gload_lds16(const void* g, void* l) {
    __builtin_amdgcn_global_load_lds(
        (const __attribute__((address_space(1))) unsigned int*)g,
        (__attribute__((address_space(3))) unsigned int*)l, 16, 0, 0);
}

// ---------------------------------------------------------------------------
// filters[l,d] = sum_k eig_vecs[l,k] * eig_vals[k]^0.25 * w_filters[k,d]
// output f16 (conv consumes f16; staging quantized to f16 anyway)
// ---------------------------------------------------------------------------
__global__ void filters_kernel(const float* __restrict__ eig_vals,
                               const float* __restrict__ eig_vecs,
                               const float* __restrict__ w_filters,
                               u16* __restrict__ out) {
    int l = blockIdx.x;
    int d = blockIdx.y * 256 + threadIdx.x;
    __shared__ float r[K_];
    if (threadIdx.x < K_) {
        float ev = eig_vals[threadIdx.x];
        r[threadIdx.x] = eig_vecs[l * K_ + threadIdx.x] * powf(ev, 0.25f);
    }
    __syncthreads();
    float acc = 0.f;
#pragma unroll
    for (int k = 0; k < K_; k++) acc += r[k] * w_filters[k * D_ + d];
    out[(size_t)l * D_ + d] = f2h(acc);
}

// ---------------------------------------------------------------------------
__global__ __launch_bounds__(256) void cast_bf16(const float* __restrict__ in,
                                                 u16* __restrict__ out) {
    int i = blockIdx.x * 256 + threadIdx.x;
    float4 v = ((const float4*)in)[i];
    ushort4 o;
    o.x = f2bf(v.x); o.y = f2bf(v.y); o.z = f2bf(v.z); o.w = f2bf(v.w);
    ((ushort4*)out)[i] = o;
}

// ---------------------------------------------------------------------------
// fp32 [R][C] -> bf16 [C][R] transpose-cast (32x32 LDS tile)
// ---------------------------------------------------------------------------
__global__ __launch_bounds__(256) void cast_T(const float* __restrict__ in,
                                              u16* __restrict__ out, int R, int C) {
    __shared__ float t[32][33];
    int c0 = blockIdx.x * 32, r0 = blockIdx.y * 32;
    int tx = threadIdx.x & 31, ty = threadIdx.x >> 5;
#pragma unroll
    for (int p = 0; p < 4; p++)
        t[ty + p * 8][tx] = in[(size_t)(r0 + ty + p * 8) * C + c0 + tx];
    __syncthreads();
#pragma unroll
    for (int p = 0; p < 4; p++)
        out[(size_t)(c0 + ty + p * 8) * R + r0 + tx] = f2bf(t[tx][ty + p * 8]);
}

// ---------------------------------------------------------------------------
// bf16 MFMA GEMM: out = act(alpha * A @ Bt^T + bias) + resid
// qcols: columns < qcols get alpha*0.125 (fused-QKV Q-scale)
// f16out: Cb written as IEEE f16 instead of bf16
// ---------------------------------------------------------------------------
__global__ __launch_bounds__(256) void gemm_bf16(
    const u16* __restrict__ A, const u16* __restrict__ Bt,
    float* __restrict__ C, u16* __restrict__ Cb,
    int M, int N, int K, float alpha,
    const float* __restrict__ bias, const float* __restrict__ resid, int act,
    int qcols, int f16out) {
    __shared__ u16 As[4][128][8];
    __shared__ u16 Bs[4][128][8];
    int tid = threadIdx.x;
    int wid = tid >> 6, lane = tid & 63;
    int bm = blockIdx.y * 128, bn = blockIdx.x * 128;
    int wm = (wid >> 1) * 64, wn = (wid & 1) * 64;
    int q = lane >> 4, r = lane & 15;

    const u16* gA0 = A + (size_t)(bm + lane) * K + wid * 8;
    const u16* gA1 = gA0 + (size_t)64 * K;
    const u16* gB0 = Bt + (size_t)(bn + lane) * K + wid * 8;
    const u16* gB1 = gB0 + (size_t)64 * K;
    u16* lA0 = &As[wid][0][0];
    u16* lA1 = &As[wid][64][0];
    u16* lB0 = &Bs[wid][0][0];
    u16* lB1 = &Bs[wid][64][0];
    const u16* pa = &As[q][wm + r][0];
    const u16* pb = &Bs[q][wn + r][0];

    fx4 acc[4][4];
#pragma unroll
    for (int i = 0; i < 4; i++)
#pragma unroll
        for (int j = 0; j < 4; j++) acc[i][j] = (fx4){0.f, 0.f, 0.f, 0.f};

    for (int k0 = 0; k0 < K; k0 += 32) {
        if (k0) __syncthreads();
        gload_lds16(gA0 + k0, lA0);
        gload_lds16(gA1 + k0, lA1);
        gload_lds16(gB0 + k0, lB0);
        gload_lds16(gB1 + k0, lB1);
        __syncthreads();
        s16x8 a[4], b[4];
#pragma unroll
        for (int i = 0; i < 4; i++) a[i] = *(const s16x8*)(pa + i * 128);
#pragma unroll
        for (int j = 0; j < 4; j++) b[j] = *(const s16x8*)(pb + j * 128);
#pragma unroll
        for (int i = 0; i < 4; i++)
#pragma unroll
            for (int j = 0; j < 4; j++)
                acc[i][j] = __builtin_amdgcn_mfma_f32_16x16x32_bf16(
                    a[i], b[j], acc[i][j], 0, 0, 0);
    }

#pragma unroll
    for (int i = 0; i < 4; i++) {
        int row0 = bm + wm + i * 16 + q * 4;
#pragma unroll
        for (int j = 0; j < 4; j++) {
            int col = bn + wn + j * 16 + r;
            float a2 = (col < qcols) ? alpha * 0.125f : alpha;
            float bv = bias ? bias[col] : 0.f;
#pragma unroll
            for (int reg = 0; reg < 4; reg++) {
                float v = a2 * acc[i][j][reg] + bv;
                if (act) v = gelu_t(v);
                size_t idx = (size_t)(row0 + reg) * N + col;
                if (resid) v += resid[idx];
                if (C) C[idx] = v;
                else Cb[idx] = f16out ? f2h(v) : f2bf(v);
            }
        }
    }
}

// ---------------------------------------------------------------------------
// Causal per-channel conv: out[b,l,d] = sum_{t=0..l} F[t,d]*XI[b,l-t,d]
// Balanced pairing (tiles i & 31-i). f16 LDS tiles + v_dot2_f32_f16.
// v4: back to v2 staging structure (v3 prefetch regressed: +VALU, no stall
//     removed). New: (1) F and XI are f16 in global -> half the bytes;
//     (2) XCD-group swizzle: all 16 blockIdx.x sharing one (d0,b) slice
//     (XI 1MB + F 0.25MB, L2-resident) land on the same XCD's L2.
// ---------------------------------------------------------------------------
__global__ __launch_bounds__(256) void conv_k(const u16* __restrict__ F,
                                              const u16* __restrict__ XI,
                                              float* __restrict__ OUT) {
    // bijective XCD swizzle (HW round-robins linear bid over 8 XCDs):
    // xcd = bid&7 gets groups [8*xcd, 8*xcd+8); each group = 16 x-sharers.
    int bid = blockIdx.x + 16 * (blockIdx.y + 16 * blockIdx.z);
    int xcd = bid & 7, ix = bid >> 3;
    int group = xcd * 8 + (ix >> 4);
    int xblk = ix & 15;
    int d0 = (group & 15) * 64, b = group >> 4;

    __shared__ u16 xs[64][132];
    __shared__ u16 ftr[64][68];
    int tid = threadIdx.x;
    int dd = tid & 63;
    int jg = tid >> 6;
    int L0 = jg * 16;
    const u16* fcol = F + d0 + dd;
    const u16* xcol = XI + (size_t)b * L_ * D_ + d0 + dd;

#pragma unroll 1
    for (int half = 0; half < 2; half++) {
        int lt = half ? (31 - xblk) : xblk;
        int l0 = lt * 64;
        float acc[16];
#pragma unroll
        for (int i = 0; i < 16; i++) acc[i] = 0.f;

        for (int t0 = 0; t0 <= l0; t0 += 64) {
            int jb = l0 - t0 - 63;
            // stage filters reversed: ftr[d][c] = F[t0+63-c, d0+d]
#pragma unroll
            for (int mm = 0; mm < 2; mm++) {
                int base = 8 * (jg + 4 * mm);
                unsigned h[8];
#pragma unroll
                for (int k = 0; k < 8; k++)
                    h[k] = fcol[(size_t)(t0 + base + k) * D_];
                *(uint2*)&ftr[dd][56 - base] =
                    make_uint2(h[7] | (h[6] << 16), h[5] | (h[4] << 16));
                *(uint2*)&ftr[dd][60 - base] =
                    make_uint2(h[3] | (h[2] << 16), h[1] | (h[0] << 16));
            }
            // stage xi window: xs[d][c] = XI[jb+c, d]  (zero outside [0,L))
            if (jb >= 0 && jb + 127 < L_) {
#pragma unroll
                for (int mm = 0; mm < 4; mm++) {
                    int c0 = 8 * (jg + 4 * mm);
                    unsigned x[8];
#pragma unroll
                    for (int k = 0; k < 8; k++)
                        x[k] = xcol[(size_t)(jb + c0 + k) * D_];
                    *(uint2*)&xs[dd][c0] =
                        make_uint2(x[0] | (x[1] << 16), x[2] | (x[3] << 16));
                    *(uint2*)&xs[dd][c0 + 4] =
                        make_uint2(x[4] | (x[5] << 16), x[6] | (x[7] << 16));
                }
            } else {
#pragma unroll
                for (int mm = 0; mm < 4; mm++) {
                    int c0 = 8 * (jg + 4 * mm);
                    unsigned x[8];
#pragma unroll
                    for (int k = 0; k < 8; k++) {
                        int j = jb + c0 + k;
                        x[k] = (j >= 0 && j < L_)
                            ? (unsigned)xcol[(size_t)j * D_] : 0u;
                    }
                    *(uint2*)&xs[dd][c0] =
                        make_uint2(x[0] | (x[1] << 16), x[2] | (x[3] << 16));
                    *(uint2*)&xs[dd][c0 + 4] =
                        make_uint2(x[4] | (x[5] << 16), x[6] | (x[7] << 16));
                }
            }
            __syncthreads();

            // init window: E[j]=(W[2j],W[2j+1]) j=0..7; O[j]=(W[2j+1],W[2j+2])
            unsigned E[10], O[10];
            {
                uint2 w0 = *(const uint2*)&xs[dd][L0];
                uint2 w1 = *(const uint2*)&xs[dd][L0 + 4];
                uint2 w2 = *(const uint2*)&xs[dd][L0 + 8];
                uint2 w3 = *(const uint2*)&xs[dd][L0 + 12];
                E[0] = w0.x; E[1] = w0.y; E[2] = w1.x; E[3] = w1.y;
                E[4] = w2.x; E[5] = w2.y; E[6] = w3.x; E[7] = w3.y;
#pragma unroll
                for (int j = 0; j < 7; j++)
                    O[j] = __builtin_amdgcn_alignbit(E[j + 1], E[j], 16);
            }
#pragma unroll
            for (int s = 0; s < 16; s++) {
                const int h = (2 * s) % 10;
                uint2 nx = *(const uint2*)&xs[dd][L0 + 16 + 4 * s];
                E[(h + 8) % 10] = nx.x;
                E[(h + 9) % 10] = nx.y;
                O[(h + 7) % 10] = __builtin_amdgcn_alignbit(E[(h + 8) % 10], E[(h + 7) % 10], 16);
                O[(h + 8) % 10] = __builtin_amdgcn_alignbit(E[(h + 9) % 10], E[(h + 8) % 10], 16);
                uint2 fr = *(const uint2*)&ftr[dd][4 * s];
                h2 f01 = __builtin_bit_cast(h2, fr.x);
                h2 f23 = __builtin_bit_cast(h2, fr.y);
#pragma unroll
                for (int i = 0; i < 16; i += 2) {
                    const int p = (h + i / 2) % 10;
                    const int p1 = (h + i / 2 + 1) % 10;
                    acc[i] = __builtin_amdgcn_fdot2(f01, __builtin_bit_cast(h2, E[p]), acc[i], false);
                    acc[i] = __builtin_amdgcn_fdot2(f23, __builtin_bit_cast(h2, E[p1]), acc[i], false);
                    acc[i + 1] = __builtin_amdgcn_fdot2(f01, __builtin_bit_cast(h2, O[p]), acc[i + 1], false);
                    acc[i + 1] = __builtin_amdgcn_fdot2(f23, __builtin_bit_cast(h2, O[p1]), acc[i + 1], false);
                }
            }
            __syncthreads();
        }
#pragma unroll
        for (int i = 0; i < 16; i++)
            OUT[((size_t)b * L_ + l0 + L0 + i) * D_ + d0 + dd] = acc[i];
    }
}

// ---------------------------------------------------------------------------
// LayerNorm -> bf16 out (row = 1024), eps 1e-6
// ---------------------------------------------------------------------------
__global__ __launch_bounds__(256) void layernorm_bf16(const float* __restrict__ x,
                                                      const float* __restrict__ scale,
                                                      const float* __restrict__ bias,
                                                      u16* __restrict__ y) {
    size_t row = blockIdx.x;
    int tid = threadIdx.x;
    const float4 v = *(const float4*)&x[row * D_ + tid * 4];
    float s = v.x + v.y + v.z + v.w;
    float q = v.x * v.x + v.y * v.y + v.z * v.z + v.w * v.w;
#pragma unroll
    for (int off = 32; off >= 1; off >>= 1) {
        s += __shfl_xor(s, off, 64);
        q += __shfl_xor(q, off, 64);
    }
    __shared__ float ss[4], sq[4];
    int w = tid >> 6;
    if ((tid & 63) == 0) { ss[w] = s; sq[w] = q; }
    __syncthreads();
    s = ss[0] + ss[1] + ss[2] + ss[3];
    q = sq[0] + sq[1] + sq[2] + sq[3];
    float mean = s * (1.f / D_);
    float var = q * (1.f / D_) - mean * mean;
    float r = rsqrtf(var + 1e-6f);
    const float4 sc = *(const float4*)&scale[tid * 4];
    const float4 bi = *(const float4*)&bias[tid * 4];
    ushort4 o;
    o.x = f2bf((v.x - mean) * r * sc.x + bi.x);
    o.y = f2bf((v.y - mean) * r * sc.y + bi.y);
    o.z = f2bf((v.z - mean) * r * sc.z + bi.z);
    o.w = f2bf((v.w - mean) * r * sc.w + bi.w);
    *(ushort4*)&y[row * D_ + tid * 4] = o;
}

// ---------------------------------------------------------------------------
// MFMA flash attention, TQ=128. Q,K,V are column slices of the fused
// [B*L, 3072] bf16 QKV buffer (stride 3072); Q pre-scaled. Out bf16 [M,1024].
// no-max softmax (scores bounded) + K/V register prefetch.
// ---------------------------------------------------------------------------
__global__ __launch_bounds__(256) void attn_mfma(const u16* __restrict__ Qg,
                                                 const u16* __restrict__ Kg,
                                                 const u16* __restrict__ Vg,
                                                 u16* __restrict__ Og) {
    const int QSTR = 3072;
    int q0 = blockIdx.x * 128;
    int b = blockIdx.y >> 4, h = blockIdx.y & 15;
    __shared__ __align__(16) u16 qs[128 * 72];
    __shared__ __align__(16) u16 ks[64 * 72];
    __shared__ __align__(16) u16 vt[64 * 72];   // V^T: [hd][s]
    int tid = threadIdx.x;
    int w = tid >> 6, lane = tid & 63;
    int quad = lane >> 4, l15 = lane & 15;
    const size_t base = (size_t)b * L_ * QSTR + h * HD_;

    // stage Q tile (once)
#pragma unroll
    for (int i = tid; i < 128 * 8; i += 256) {
        int r = i >> 3, c = i & 7;
        *(uint4*)&qs[r * 72 + c * 8] =
            *(const uint4*)&Qg[base + (size_t)(q0 + r) * QSTR + c * 8];
    }
    __syncthreads();
    s16x8 aq[2][2];
#pragma unroll
    for (int mi = 0; mi < 2; mi++)
#pragma unroll
        for (int kb = 0; kb < 2; kb++)
            aq[mi][kb] = *(const s16x8*)&qs[(w * 32 + mi * 16 + l15) * 72 + kb * 32 + quad * 8];

    float rsacc[2][4];
    fx4 o[2][4];
#pragma unroll
    for (int mi = 0; mi < 2; mi++)
#pragma unroll
        for (int i = 0; i < 4; i++) {
            rsacc[mi][i] = 0.f;
            o[mi][i] = (fx4){0.f, 0.f, 0.f, 0.f};
        }
    u16* psw = qs + w * 32 * 72;   // wave-private (rows this wave hoisted)

    // K/V prefetch pointers (each thread stages 2 uint4 of K, 2 uint4 of V)
    int kr0 = tid >> 3, kc = tid & 7;
    const u16* kg0 = Kg + base + (size_t)kr0 * QSTR + kc * 8;
    const u16* kg1 = kg0 + (size_t)32 * QSTR;
    const u16* vg = Vg + base + (size_t)lane * QSTR + w * 8;
    uint4 kp0 = *(const uint4*)kg0;
    uint4 kp1 = *(const uint4*)kg1;
    uint4 vp0 = *(const uint4*)vg;
    uint4 vp1 = *(const uint4*)(vg + 32);

    for (int s0 = 0; s0 < L_; s0 += 64) {
        __syncthreads();   // prior tile's LDS reads complete
        *(uint4*)&ks[kr0 * 72 + kc * 8] = kp0;
        *(uint4*)&ks[(kr0 + 32) * 72 + kc * 8] = kp1;
        {
            u16 t0[8], t1[8];
            *(uint4*)t0 = vp0;
            *(uint4*)t1 = vp1;
#pragma unroll
            for (int j = 0; j < 8; j++) vt[(w * 8 + j) * 72 + lane] = t0[j];
#pragma unroll
            for (int j = 0; j < 8; j++) vt[(w * 8 + 32 + j) * 72 + lane] = t1[j];
        }
        if (s0 + 64 < L_) {
            size_t off = (size_t)(s0 + 64) * QSTR;
            kp0 = *(const uint4*)(kg0 + off);
            kp1 = *(const uint4*)(kg1 + off);
            vp0 = *(const uint4*)(vg + off);
            vp1 = *(const uint4*)(vg + off + 32);
        }
        __syncthreads();

        // S = Q K^T : per-wave 32q x 64s
        fx4 sv[2][4];
#pragma unroll
        for (int mi = 0; mi < 2; mi++)
#pragma unroll
            for (int nt = 0; nt < 4; nt++) sv[mi][nt] = (fx4){0.f, 0.f, 0.f, 0.f};
#pragma unroll
        for (int kb = 0; kb < 2; kb++)
#pragma unroll
            for (int nt = 0; nt < 4; nt++) {
                s16x8 bk = *(const s16x8*)&ks[(nt * 16 + l15) * 72 + kb * 32 + quad * 8];
#pragma unroll
                for (int mi = 0; mi < 2; mi++)
                    sv[mi][nt] = __builtin_amdgcn_mfma_f32_16x16x32_bf16(
                        aq[mi][kb], bk, sv[mi][nt], 0, 0, 0);
            }

        // linear softmax accumulation (no max subtraction; scores bounded)
#pragma unroll
        for (int mi = 0; mi < 2; mi++)
#pragma unroll
            for (int nt = 0; nt < 4; nt++)
#pragma unroll
                for (int reg = 0; reg < 4; reg++) {
                    float p = __expf(sv[mi][nt][reg]);
                    rsacc[mi][reg] += p;
                    psw[(mi * 16 + quad * 4 + reg) * 72 + nt * 16 + l15] = f2bf(p);
                }

        // PV: O += P V
#pragma unroll
        for (int kb = 0; kb < 2; kb++) {
            s16x8 ap[2];
#pragma unroll
            for (int mi = 0; mi < 2; mi++)
                ap[mi] = *(const s16x8*)&psw[(mi * 16 + l15) * 72 + kb * 32 + quad * 8];
#pragma unroll
            for (int nt = 0; nt < 4; nt++) {
                s16x8 bv = *(const s16x8*)&vt[(nt * 16 + l15) * 72 + kb * 32 + quad * 8];
#pragma unroll
                for (int mi = 0; mi < 2; mi++)
                    o[mi][nt] = __builtin_amdgcn_mfma_f32_16x16x32_bf16(
                        ap[mi], bv, o[mi][nt], 0, 0, 0);
            }
        }
    }
    // epilogue: reduce row-sums across the 16 s-lanes, then O / lsum -> bf16
    float lsum[2][4];
#pragma unroll
    for (int mi = 0; mi < 2; mi++)
#pragma unroll
        for (int reg = 0; reg < 4; reg++) {
            float r = rsacc[mi][reg];
#pragma unroll
            for (int off = 8; off >= 1; off >>= 1)
                r += __shfl_xor(r, off, 16);
            lsum[mi][reg] = r;
        }
    const size_t baseo = (size_t)b * L_ * 1024 + h * HD_;
#pragma unroll
    for (int mi = 0; mi < 2; mi++)
#pragma unroll
        for (int reg = 0; reg < 4; reg++) {
            float inv = 1.f / lsum[mi][reg];
            size_t row = baseo +
                (size_t)(q0 + w * 32 + mi * 16 + quad * 4 + reg) * 1024;
#pragma unroll
            for (int nt = 0; nt < 4; nt++)
                Og[row + nt * 16 + l15] = f2bf(o[mi][nt][reg] * inv);
        }
}

// ---------------------------------------------------------------------------
extern "C" void kernel_launch(void* const* d_in, const int* in_sizes, int n_in,
                              void* d_out, int out_size, void* d_ws, size_t ws_size,
                              hipStream_t stream) {
    const float* inputs   = (const float*)d_in[0];
    const float* eig_vals = (const float*)d_in[1];
    const float* eig_vecs = (const float*)d_in[2];
    const float* w_filt   = (const float*)d_in[3];
    const float* w_inp    = (const float*)d_in[4];
    const float* ln1_s    = (const float*)d_in[5];
    const float* ln1_b    = (const float*)d_in[6];
    const float* wq       = (const float*)d_in[7];
    const float* wk       = (const float*)d_in[8];
    const float* wv       = (const float*)d_in[9];
    const float* wo       = (const float*)d_in[10];
    const float* ln2_s    = (const float*)d_in[11];
    const float* ln2_b    = (const float*)d_in[12];
    const float* w1       = (const float*)d_in[13];
    const float* b1       = (const float*)d_in[14];
    const float* w2       = (const float*)d_in[15];
    const float* b2       = (const float*)d_in[16];
    float* out = (float*)d_out;
    char* ws = (char*)d_ws;
    const size_t MB = 1u << 20;
    // Region plan (peak 192MB):
    //   0-16  : INb bf16                 [dead after XI gemm]
    //  16-42  : weights: WIt@16, WQKVt@18(6MB), WOt@24, W1t@26, W2t@34
    //  48-64  : XIH f16 [M,1024]         [dead after conv]
    //  48-112 : HID bf16 (MLP phase; XIH+STU dead by then)
    //  80-112 : STU fp32                 [dead after WO gemm]
    // 112-128 : XN bf16                  [dead after QKV gemm]
    // 128-176 : QKV bf16 fused [M,3072]  [dead after attn]
    // 128-160 : Xb fp32 (after attn)
    // 160-176 : YN bf16 (after WO gemm)
    // 176-180 : FvH f16 [L,1024]         [dead after conv]
    // 176-192 : Ab bf16 (after attn)     [dead after WO gemm]
    u16*   INb   = (u16*)(ws + 0 * MB);
    u16*   WIt   = (u16*)(ws + 16 * MB);
    u16*   WQKVt = (u16*)(ws + 18 * MB);
    u16*   WOt   = (u16*)(ws + 24 * MB);
    u16*   W1t   = (u16*)(ws + 26 * MB);
    u16*   W2t   = (u16*)(ws + 34 * MB);
    u16*   XIH   = (u16*)(ws + 48 * MB);
    u16*   HID   = (u16*)(ws + 48 * MB);
    float* STU   = (float*)(ws + 80 * MB);
    u16*   XN    = (u16*)(ws + 112 * MB);
    u16*   QKV   = (u16*)(ws + 128 * MB);
    float* Xb    = (float*)(ws + 128 * MB);
    u16*   YN    = (u16*)(ws + 160 * MB);
    u16*   FvH   = (u16*)(ws + 176 * MB);
    u16*   Ab    = (u16*)(ws + 176 * MB);

    const int M = B_ * L_;

    cast_bf16<<<(M * D_ / 4 + 255) / 256, 256, 0, stream>>>(inputs, INb);
    cast_T<<<dim3(D_ / 32, D_ / 32), 256, 0, stream>>>(w_inp, WIt, D_, D_);
    cast_T<<<dim3(D_ / 32, D_ / 32), 256, 0, stream>>>(wq, WQKVt + 0 * D_ * D_, D_, D_);
    cast_T<<<dim3(D_ / 32, D_ / 32), 256, 0, stream>>>(wk, WQKVt + 1 * D_ * D_, D_, D_);
    cast_T<<<dim3(D_ / 32, D_ / 32), 256, 0, stream>>>(wv, WQKVt + 2 * D_ * D_, D_, D_);
    cast_T<<<dim3(D_ / 32, D_ / 32), 256, 0, stream>>>(wo, WOt, D_, D_);
    cast_T<<<dim3(MLP_ / 32, D_ / 32), 256, 0, stream>>>(w1, W1t, D_, MLP_);
    cast_T<<<dim3(D_ / 32, MLP_ / 32), 256, 0, stream>>>(w2, W2t, MLP_, D_);

    filters_kernel<<<dim3(L_, D_ / 256), 256, 0, stream>>>(eig_vals, eig_vecs, w_filt, FvH);

    // XI = INb @ WIt^T, written directly as f16
    gemm_bf16<<<dim3(D_ / 128, M / 128), 256, 0, stream>>>(
        INb, WIt, nullptr, XIH, M, D_, D_, 1.f, nullptr, nullptr, 0, 0, 1);
    conv_k<<<dim3(16, D_ / 64, B_), 256, 0, stream>>>(FvH, XIH, STU);
    layernorm_bf16<<<M, 256, 0, stream>>>(STU, ln1_s, ln1_b, XN);
    // fused QKV (cols<1024 get the 1/sqrt(hd) Q-scale)
    gemm_bf16<<<dim3(3 * D_ / 128, M / 128), 256, 0, stream>>>(
        XN, WQKVt, nullptr, QKV, M, 3 * D_, D_, 1.f, nullptr, nullptr, 0, D_, 0);
    attn_mfma<<<dim3(L_ / 128, B_ * H_), 256, 0, stream>>>(
        QKV, QKV + D_, QKV + 2 * D_, Ab);
    gemm_bf16<<<dim3(D_ / 128, M / 128), 256, 0, stream>>>(
        Ab, WOt, Xb, nullptr, M, D_, D_, 1.f, nullptr, STU, 0, 0, 0);
    layernorm_bf16<<<M, 256, 0, stream>>>(Xb, ln2_s, ln2_b, YN);
    gemm_bf16<<<dim3(MLP_ / 128, M / 128), 256, 0, stream>>>(
        YN, W1t, nullptr, HID, M, MLP_, D_, 1.f, b1, nullptr, 1, 0, 0);
    gemm_bf16<<<dim3(D_ / 128, M / 128), 256, 0, stream>>>(
        HID, W2t, out, nullptr, M, D_, MLP_, 1.f, b2, Xb, 0, 0, 0);
}

// Round 5
// 965.504 us; speedup vs baseline: 1.0762x; 1.0507x over previous
//
#include <hip/hip_runtime.h>
#include <math.h>

#define B_ 4
#define L_ 2048
#define D_ 1024
#define H_ 16
#define HD_ 64
#define K_ 24
#define MLP_ 4096

typedef unsigned short u16;
typedef short s16x8 __attribute__((ext_vector_type(8)));
typedef float fx4 __attribute__((ext_vector_type(4)));
typedef _Float16 h2 __attribute__((ext_vector_type(2)));

__device__ __forceinline__ u16 f2bf(float f) {
    unsigned u = __float_as_uint(f);
    unsigned r = (u + 0x7fff + ((u >> 16) & 1)) >> 16;
    return (u16)r;
}

__device__ __forceinline__ u16 f2h(float f) {
    _Float16 hv = (_Float16)f;
    return __builtin_bit_cast(u16, hv);
}

__device__ __forceinline__ float gelu_t(float x) {
    float u = 0.7978845608028654f * (x + 0.044715f * x * x * x);
    return x / (1.f + __expf(-2.f * u));
}

__device__ __forceinline__ void gload_lds16(const void* g, void* l) {
    __builtin_amdgcn_global_load_lds(
        (const __attribute__((address_space(1))) unsigned int*)g,
        (__attribute__((address_space(3))) unsigned int*)l, 16, 0, 0);
}

// ---------------------------------------------------------------------------
// Spectral filters, computed directly transposed+reversed:
// FvT[d][l0 + (l&63)^63] = sum_k eig_vecs[l,k]*ev^0.25[k]*w_filters[k,d] (f16)
// so conv can read taps ascending-contiguous per d-row.
// ---------------------------------------------------------------------------
__global__ __launch_bounds__(256) void filters_T(const float* __restrict__ eig_vals,
                                                 const float* __restrict__ eig_vecs,
                                                 const float* __restrict__ w_filters,
                                                 u16* __restrict__ outT) {
    int l0 = blockIdx.x * 64, d0 = blockIdx.y * 64;
    __shared__ float ev25[K_];
    __shared__ float rr[64][25];
    __shared__ float wfs[K_][64];
    int tid = threadIdx.x;
    if (tid < K_) ev25[tid] = powf(eig_vals[tid], 0.25f);
    __syncthreads();
    for (int i = tid; i < 64 * K_; i += 256)
        rr[i / K_][i % K_] = eig_vecs[l0 * K_ + i];
    for (int i = tid; i < K_ * 64; i += 256) {
        int k = i >> 6, dd = i & 63;
        wfs[k][dd] = ev25[k] * w_filters[k * D_ + d0 + dd];
    }
    __syncthreads();
    int lane = tid & 63, w = tid >> 6;
    float acc[16];
#pragma unroll
    for (int i = 0; i < 16; i++) acc[i] = 0.f;
#pragma unroll
    for (int k = 0; k < K_; k++) {
        float rv = rr[lane][k];
#pragma unroll
        for (int i = 0; i < 16; i++) acc[i] += rv * wfs[k][w * 16 + i];
    }
#pragma unroll
    for (int i = 0; i < 16; i++)
        outT[(size_t)(d0 + w * 16 + i) * L_ + l0 + (lane ^ 63)] = f2h(acc[i]);
}

// ---------------------------------------------------------------------------
// f16 [M][D] -> f16 [D][M] transpose (64x64 LDS tiles)
// ---------------------------------------------------------------------------
__global__ __launch_bounds__(256) void transpose_h(const u16* __restrict__ in,
                                                   u16* __restrict__ outT) {
    __shared__ u16 t[64][68];
    int m0 = blockIdx.x * 64, d0 = blockIdx.y * 64;
    int tid = threadIdx.x;
    int r = tid >> 3, c8 = (tid & 7) * 8;
#pragma unroll
    for (int p = 0; p < 2; p++) {
        uint4 X = *(const uint4*)&in[(size_t)(m0 + r + p * 32) * D_ + d0 + c8];
        *(uint2*)&t[r + p * 32][c8] = make_uint2(X.x, X.y);
        *(uint2*)&t[r + p * 32][c8 + 4] = make_uint2(X.z, X.w);
    }
    __syncthreads();
    int dr = tid >> 3, mc = (tid & 7) * 8;
#pragma unroll
    for (int p = 0; p < 2; p++) {
        int d = dr + p * 32;
        unsigned h[8];
#pragma unroll
        for (int j = 0; j < 8; j++) h[j] = t[mc + j][d];
        uint4 o;
        o.x = h[0] | (h[1] << 16); o.y = h[2] | (h[3] << 16);
        o.z = h[4] | (h[5] << 16); o.w = h[6] | (h[7] << 16);
        *(uint4*)&outT[(size_t)(d0 + d) * (size_t)(B_ * L_) + m0 + mc] = o;
    }
}

// ---------------------------------------------------------------------------
__global__ __launch_bounds__(256) void cast_bf16(const float* __restrict__ in,
                                                 u16* __restrict__ out) {
    int i = blockIdx.x * 256 + threadIdx.x;
    float4 v = ((const float4*)in)[i];
    ushort4 o;
    o.x = f2bf(v.x); o.y = f2bf(v.y); o.z = f2bf(v.z); o.w = f2bf(v.w);
    ((ushort4*)out)[i] = o;
}

// ---------------------------------------------------------------------------
// fp32 [R][C] -> bf16 [C][R] transpose-cast (32x32 LDS tile)
// ---------------------------------------------------------------------------
__global__ __launch_bounds__(256) void cast_T(const float* __restrict__ in,
                                              u16* __restrict__ out, int R, int C) {
    __shared__ float t[32][33];
    int c0 = blockIdx.x * 32, r0 = blockIdx.y * 32;
    int tx = threadIdx.x & 31, ty = threadIdx.x >> 5;
#pragma unroll
    for (int p = 0; p < 4; p++)
        t[ty + p * 8][tx] = in[(size_t)(r0 + ty + p * 8) * C + c0 + tx];
    __syncthreads();
#pragma unroll
    for (int p = 0; p < 4; p++)
        out[(size_t)(c0 + ty + p * 8) * R + r0 + tx] = f2bf(t[tx][ty + p * 8]);
}

// ---------------------------------------------------------------------------
// bf16 MFMA GEMM: out = act(alpha * A @ Bt^T + bias) + resid
// qcols: columns < qcols get alpha*0.125 (fused-QKV Q-scale)
// f16out: Cb written as IEEE f16.  XCD swizzle: same-bm panels -> same XCD L2.
// ---------------------------------------------------------------------------
__global__ __launch_bounds__(256) void gemm_bf16(
    const u16* __restrict__ A, const u16* __restrict__ Bt,
    float* __restrict__ C, u16* __restrict__ Cb,
    int M, int N, int K, float alpha,
    const float* __restrict__ bias, const float* __restrict__ resid, int act,
    int qcols, int f16out) {
    __shared__ u16 As[4][128][8];
    __shared__ u16 Bs[4][128][8];
    int tid = threadIdx.x;
    int wid = tid >> 6, lane = tid & 63;
    int bxs = blockIdx.x, bys = blockIdx.y;
    if ((gridDim.y & 7) == 0) {
        int bid = blockIdx.x + gridDim.x * blockIdx.y;
        int xcd = bid & 7, idx = bid >> 3;
        bys = xcd + 8 * (idx / gridDim.x);
        bxs = idx % gridDim.x;
    }
    int bm = bys * 128, bn = bxs * 128;
    int wm = (wid >> 1) * 64, wn = (wid & 1) * 64;
    int q = lane >> 4, r = lane & 15;

    const u16* gA0 = A + (size_t)(bm + lane) * K + wid * 8;
    const u16* gA1 = gA0 + (size_t)64 * K;
    const u16* gB0 = Bt + (size_t)(bn + lane) * K + wid * 8;
    const u16* gB1 = gB0 + (size_t)64 * K;
    u16* lA0 = &As[wid][0][0];
    u16* lA1 = &As[wid][64][0];
    u16* lB0 = &Bs[wid][0][0];
    u16* lB1 = &Bs[wid][64][0];
    const u16* pa = &As[q][wm + r][0];
    const u16* pb = &Bs[q][wn + r][0];

    fx4 acc[4][4];
#pragma unroll
    for (int i = 0; i < 4; i++)
#pragma unroll
        for (int j = 0; j < 4; j++) acc[i][j] = (fx4){0.f, 0.f, 0.f, 0.f};

    for (int k0 = 0; k0 < K; k0 += 32) {
        if (k0) __syncthreads();
        gload_lds16(gA0 + k0, lA0);
        gload_lds16(gA1 + k0, lA1);
        gload_lds16(gB0 + k0, lB0);
        gload_lds16(gB1 + k0, lB1);
        __syncthreads();
        s16x8 a[4], b[4];
#pragma unroll
        for (int i = 0; i < 4; i++) a[i] = *(const s16x8*)(pa + i * 128);
#pragma unroll
        for (int j = 0; j < 4; j++) b[j] = *(const s16x8*)(pb + j * 128);
#pragma unroll
        for (int i = 0; i < 4; i++)
#pragma unroll
            for (int j = 0; j < 4; j++)
                acc[i][j] = __builtin_amdgcn_mfma_f32_16x16x32_bf16(
                    a[i], b[j], acc[i][j], 0, 0, 0);
    }

#pragma unroll
    for (int i = 0; i < 4; i++) {
        int row0 = bm + wm + i * 16 + q * 4;
#pragma unroll
        for (int j = 0; j < 4; j++) {
            int col = bn + wn + j * 16 + r;
            float a2 = (col < qcols) ? alpha * 0.125f : alpha;
            float bv = bias ? bias[col] : 0.f;
#pragma unroll
            for (int reg = 0; reg < 4; reg++) {
                float v = a2 * acc[i][j][reg] + bv;
                if (act) v = gelu_t(v);
                size_t idx = (size_t)(row0 + reg) * N + col;
                if (resid) v += resid[idx];
                if (C) C[idx] = v;
                else Cb[idx] = f16out ? f2h(v) : f2bf(v);
            }
        }
    }
}

// ---------------------------------------------------------------------------
// Causal per-channel conv: out[b,l,d] = sum_{t=0..l} F[t,d]*XI[b,l-t,d]
// v5: transposed f16 inputs (FT = filters [d][t] reversed-within-64;
//     XT = xi [d][m]) -> staging is 6 coalesced b128 loads, no packing.
//     Window shifted -1 (jb = l0-t0-64, 8-aligned): Q ring holds direct
//     b64 pairs, E derived via alignbit (same op count as before; the old
//     E/O roles swap). Only the t0==l0 step needs zero-fill (chunk level).
//     __launch_bounds__(256,6): VGPR cap 85 (LDS limits to 6 blocks/CU).
// ---------------------------------------------------------------------------
__global__ __launch_bounds__(256, 6) void conv_k(const u16* __restrict__ FT,
                                                 const u16* __restrict__ XT,
                                                 float* __restrict__ OUT) {
    // bijective XCD swizzle: 16 x-sharers of one (d0,b) slice -> same XCD L2
    int bid = blockIdx.x + 16 * (blockIdx.y + 16 * blockIdx.z);
    int xcd = bid & 7, ix = bid >> 3;
    int group = xcd * 8 + (ix >> 4);
    int xblk = ix & 15;
    int d0 = (group & 15) * 64, b = group >> 4;

    __shared__ u16 xs[64][132];
    __shared__ u16 ftr[64][68];
    int tid = threadIdx.x;
    int dd = tid & 63;
    int jg = tid >> 6;
    int L0 = jg * 16;
    // staging thread mapping (coalesced global reads):
    int frow = tid >> 3, fq = (tid & 7) * 8;        // filters: 32 rows/pass
    int xrow = tid >> 4, xq = (tid & 15) * 8;       // xi: 16 rows/pass
    const u16* fbase = FT + (size_t)(d0 + frow) * L_ + fq;
    const u16* xbase = XT + (size_t)(d0 + xrow) * (B_ * L_) + (size_t)b * L_ + xq;

#pragma unroll 1
    for (int half = 0; half < 2; half++) {
        int lt = half ? (31 - xblk) : xblk;
        int l0 = lt * 64;
        float acc[16];
#pragma unroll
        for (int i = 0; i < 16; i++) acc[i] = 0.f;

        for (int t0 = 0; t0 <= l0; t0 += 64) {
            int jb = l0 - t0 - 64;
            // stage filters: FT rows are pre-reversed; ascending copy
#pragma unroll
            for (int p = 0; p < 2; p++) {
                uint4 Fq = *(const uint4*)(fbase + (size_t)p * 32 * L_ + t0);
                *(uint2*)&ftr[frow + p * 32][fq] = make_uint2(Fq.x, Fq.y);
                *(uint2*)&ftr[frow + p * 32][fq + 4] = make_uint2(Fq.z, Fq.w);
            }
            // stage xi window: xs[d][c] = XT[d][b*L + jb + c], c in [0,128)
            if (jb >= 0) {
#pragma unroll
                for (int p = 0; p < 4; p++) {
                    uint4 Xq = *(const uint4*)(xbase + (size_t)p * 16 * (B_ * L_) + jb);
                    *(uint2*)&xs[xrow + p * 16][xq] = make_uint2(Xq.x, Xq.y);
                    *(uint2*)&xs[xrow + p * 16][xq + 4] = make_uint2(Xq.z, Xq.w);
                }
            } else {
                // t0 == l0 (jb = -64): c = xq < 64 -> zeros; c >= 64 -> j = c-64
#pragma unroll
                for (int p = 0; p < 4; p++) {
                    uint4 Xq = make_uint4(0, 0, 0, 0);
                    if (xq >= 64)
                        Xq = *(const uint4*)(xbase + (size_t)p * 16 * (B_ * L_) - 64);
                    *(uint2*)&xs[xrow + p * 16][xq] = make_uint2(Xq.x, Xq.y);
                    *(uint2*)&xs[xrow + p * 16][xq + 4] = make_uint2(Xq.z, Xq.w);
                }
            }
            __syncthreads();

            // Q ring: Q[j] = (xs[2j], xs[2j+1]) rel L0; E[j] = (xs[2j+1], xs[2j+2])
            unsigned Q[10], E[10];
            {
                uint2 q0 = *(const uint2*)&xs[dd][L0];
                uint2 q1 = *(const uint2*)&xs[dd][L0 + 4];
                uint2 q2 = *(const uint2*)&xs[dd][L0 + 8];
                uint2 q3 = *(const uint2*)&xs[dd][L0 + 12];
                Q[0] = q0.x; Q[1] = q0.y; Q[2] = q1.x; Q[3] = q1.y;
                Q[4] = q2.x; Q[5] = q2.y; Q[6] = q3.x; Q[7] = q3.y;
#pragma unroll
                for (int j = 0; j < 7; j++)
                    E[j] = __builtin_amdgcn_alignbit(Q[j + 1], Q[j], 16);
            }
#pragma unroll
            for (int s = 0; s < 16; s++) {
                const int h = (2 * s) % 10;
                uint2 nx = *(const uint2*)&xs[dd][L0 + 16 + 4 * s];
                Q[(h + 8) % 10] = nx.x;
                Q[(h + 9) % 10] = nx.y;
                E[(h + 7) % 10] = __builtin_amdgcn_alignbit(Q[(h + 8) % 10], Q[(h + 7) % 10], 16);
                E[(h + 8) % 10] = __builtin_amdgcn_alignbit(Q[(h + 9) % 10], Q[(h + 8) % 10], 16);
                uint2 fr = *(const uint2*)&ftr[dd][4 * s];
                h2 f01 = __builtin_bit_cast(h2, fr.x);
                h2 f23 = __builtin_bit_cast(h2, fr.y);
#pragma unroll
                for (int i = 0; i < 16; i += 2) {
                    const int p = (h + i / 2) % 10;
                    const int p1 = (h + i / 2 + 1) % 10;
                    const int p2 = (h + i / 2 + 2) % 10;
                    acc[i] = __builtin_amdgcn_fdot2(f01, __builtin_bit_cast(h2, E[p]), acc[i], false);
                    acc[i] = __builtin_amdgcn_fdot2(f23, __builtin_bit_cast(h2, E[p1]), acc[i], false);
                    acc[i + 1] = __builtin_amdgcn_fdot2(f01, __builtin_bit_cast(h2, Q[p1]), acc[i + 1], false);
                    acc[i + 1] = __builtin_amdgcn_fdot2(f23, __builtin_bit_cast(h2, Q[p2]), acc[i + 1], false);
                }
            }
            __syncthreads();
        }
#pragma unroll
        for (int i = 0; i < 16; i++)
            OUT[((size_t)b * L_ + l0 + L0 + i) * D_ + d0 + dd] = acc[i];
    }
}

// ---------------------------------------------------------------------------
// LayerNorm -> bf16 out (row = 1024), eps 1e-6
// ---------------------------------------------------------------------------
__global__ __launch_bounds__(256) void layernorm_bf16(const float* __restrict__ x,
                                                      const float* __restrict__ scale,
                                                      const float* __restrict__ bias,
                                                      u16* __restrict__ y) {
    size_t row = blockIdx.x;
    int tid = threadIdx.x;
    const float4 v = *(const float4*)&x[row * D_ + tid * 4];
    float s = v.x + v.y + v.z + v.w;
    float q = v.x * v.x + v.y * v.y + v.z * v.z + v.w * v.w;
#pragma unroll
    for (int off = 32; off >= 1; off >>= 1) {
        s += __shfl_xor(s, off, 64);
        q += __shfl_xor(q, off, 64);
    }
    __shared__ float ss[4], sq[4];
    int w = tid >> 6;
    if ((tid & 63) == 0) { ss[w] = s; sq[w] = q; }
    __syncthreads();
    s = ss[0] + ss[1] + ss[2] + ss[3];
    q = sq[0] + sq[1] + sq[2] + sq[3];
    float mean = s * (1.f / D_);
    float var = q * (1.f / D_) - mean * mean;
    float r = rsqrtf(var + 1e-6f);
    const float4 sc = *(const float4*)&scale[tid * 4];
    const float4 bi = *(const float4*)&bias[tid * 4];
    ushort4 o;
    o.x = f2bf((v.x - mean) * r * sc.x + bi.x);
    o.y = f2bf((v.y - mean) * r * sc.y + bi.y);
    o.z = f2bf((v.z - mean) * r * sc.z + bi.z);
    o.w = f2bf((v.w - mean) * r * sc.w + bi.w);
    *(ushort4*)&y[row * D_ + tid * 4] = o;
}

// ---------------------------------------------------------------------------
// MFMA flash attention, TQ=128. Q,K,V are column slices of the fused
// [B*L, 3072] bf16 QKV buffer (stride 3072); Q pre-scaled. Out bf16 [M,1024].
// no-max softmax (scores bounded) + K/V register prefetch + XCD swizzle.
// ---------------------------------------------------------------------------
__global__ __launch_bounds__(256) void attn_mfma(const u16* __restrict__ Qg,
                                                 const u16* __restrict__ Kg,
                                                 const u16* __restrict__ Vg,
                                                 u16* __restrict__ Og) {
    const int QSTR = 3072;
    int bxs = blockIdx.x, bys = blockIdx.y;
    {
        int bid = blockIdx.x + gridDim.x * blockIdx.y;
        int xcd = bid & 7, idx = bid >> 3;
        bys = xcd + 8 * (idx / gridDim.x);
        bxs = idx % gridDim.x;
    }
    int q0 = bxs * 128;
    int b = bys >> 4, h = bys & 15;
    __shared__ __align__(16) u16 qs[128 * 72];
    __shared__ __align__(16) u16 ks[64 * 72];
    __shared__ __align__(16) u16 vt[64 * 72];   // V^T: [hd][s]
    int tid = threadIdx.x;
    int w = tid >> 6, lane = tid & 63;
    int quad = lane >> 4, l15 = lane & 15;
    const size_t base = (size_t)b * L_ * QSTR + h * HD_;

    // stage Q tile (once)
#pragma unroll
    for (int i = tid; i < 128 * 8; i += 256) {
        int r = i >> 3, c = i & 7;
        *(uint4*)&qs[r * 72 + c * 8] =
            *(const uint4*)&Qg[base + (size_t)(q0 + r) * QSTR + c * 8];
    }
    __syncthreads();
    s16x8 aq[2][2];
#pragma unroll
    for (int mi = 0; mi < 2; mi++)
#pragma unroll
        for (int kb = 0; kb < 2; kb++)
            aq[mi][kb] = *(const s16x8*)&qs[(w * 32 + mi * 16 + l15) * 72 + kb * 32 + quad * 8];

    float rsacc[2][4];
    fx4 o[2][4];
#pragma unroll
    for (int mi = 0; mi < 2; mi++)
#pragma unroll
        for (int i = 0; i < 4; i++) {
            rsacc[mi][i] = 0.f;
            o[mi][i] = (fx4){0.f, 0.f, 0.f, 0.f};
        }
    u16* psw = qs + w * 32 * 72;   // wave-private (rows this wave hoisted)

    // K/V prefetch pointers (each thread stages 2 uint4 of K, 2 uint4 of V)
    int kr0 = tid >> 3, kc = tid & 7;
    const u16* kg0 = Kg + base + (size_t)kr0 * QSTR + kc * 8;
    const u16* kg1 = kg0 + (size_t)32 * QSTR;
    const u16* vg = Vg + base + (size_t)lane * QSTR + w * 8;
    uint4 kp0 = *(const uint4*)kg0;
    uint4 kp1 = *(const uint4*)kg1;
    uint4 vp0 = *(const uint4*)vg;
    uint4 vp1 = *(const uint4*)(vg + 32);

    for (int s0 = 0; s0 < L_; s0 += 64) {
        __syncthreads();   // prior tile's LDS reads complete
        *(uint4*)&ks[kr0 * 72 + kc * 8] = kp0;
        *(uint4*)&ks[(kr0 + 32) * 72 + kc * 8] = kp1;
        {
            u16 t0[8], t1[8];
            *(uint4*)t0 = vp0;
            *(uint4*)t1 = vp1;
#pragma unroll
            for (int j = 0; j < 8; j++) vt[(w * 8 + j) * 72 + lane] = t0[j];
#pragma unroll
            for (int j = 0; j < 8; j++) vt[(w * 8 + 32 + j) * 72 + lane] = t1[j];
        }
        if (s0 + 64 < L_) {
            size_t off = (size_t)(s0 + 64) * QSTR;
            kp0 = *(const uint4*)(kg0 + off);
            kp1 = *(const uint4*)(kg1 + off);
            vp0 = *(const uint4*)(vg + off);
            vp1 = *(const uint4*)(vg + off + 32);
        }
        __syncthreads();

        // S = Q K^T : per-wave 32q x 64s
        fx4 sv[2][4];
#pragma unroll
        for (int mi = 0; mi < 2; mi++)
#pragma unroll
            for (int nt = 0; nt < 4; nt++) sv[mi][nt] = (fx4){0.f, 0.f, 0.f, 0.f};
#pragma unroll
        for (int kb = 0; kb < 2; kb++)
#pragma unroll
            for (int nt = 0; nt < 4; nt++) {
                s16x8 bk = *(const s16x8*)&ks[(nt * 16 + l15) * 72 + kb * 32 + quad * 8];
#pragma unroll
                for (int mi = 0; mi < 2; mi++)
                    sv[mi][nt] = __builtin_amdgcn_mfma_f32_16x16x32_bf16(
                        aq[mi][kb], bk, sv[mi][nt], 0, 0, 0);
            }

        // linear softmax accumulation (no max subtraction; scores bounded)
#pragma unroll
        for (int mi = 0; mi < 2; mi++)
#pragma unroll
            for (int nt = 0; nt < 4; nt++)
#pragma unroll
                for (int reg = 0; reg < 4; reg++) {
                    float p = __expf(sv[mi][nt][reg]);
                    rsacc[mi][reg] += p;
                    psw[(mi * 16 + quad * 4 + reg) * 72 + nt * 16 + l15] = f2bf(p);
                }

        // PV: O += P V
#pragma unroll
        for (int kb = 0; kb < 2; kb++) {
            s16x8 ap[2];
#pragma unroll
            for (int mi = 0; mi < 2; mi++)
                ap[mi] = *(const s16x8*)&psw[(mi * 16 + l15) * 72 + kb * 32 + quad * 8];
#pragma unroll
            for (int nt = 0; nt < 4; nt++) {
                s16x8 bv = *(const s16x8*)&vt[(nt * 16 + l15) * 72 + kb * 32 + quad * 8];
#pragma unroll
                for (int mi = 0; mi < 2; mi++)
                    o[mi][nt] = __builtin_amdgcn_mfma_f32_16x16x32_bf16(
                        ap[mi], bv, o[mi][nt], 0, 0, 0);
            }
        }
    }
    // epilogue: reduce row-sums across the 16 s-lanes, then O / lsum -> bf16
    float lsum[2][4];
#pragma unroll
    for (int mi = 0; mi < 2; mi++)
#pragma unroll
        for (int reg = 0; reg < 4; reg++) {
            float r = rsacc[mi][reg];
#pragma unroll
            for (int off = 8; off >= 1; off >>= 1)
                r += __shfl_xor(r, off, 16);
            lsum[mi][reg] = r;
        }
    const size_t baseo = (size_t)b * L_ * 1024 + h * HD_;
#pragma unroll
    for (int mi = 0; mi < 2; mi++)
#pragma unroll
        for (int reg = 0; reg < 4; reg++) {
            float inv = 1.f / lsum[mi][reg];
            size_t row = baseo +
                (size_t)(q0 + w * 32 + mi * 16 + quad * 4 + reg) * 1024;
#pragma unroll
            for (int nt = 0; nt < 4; nt++)
                Og[row + nt * 16 + l15] = f2bf(o[mi][nt][reg] * inv);
        }
}

// ---------------------------------------------------------------------------
extern "C" void kernel_launch(void* const* d_in, const int* in_sizes, int n_in,
                              void* d_out, int out_size, void* d_ws, size_t ws_size,
                              hipStream_t stream) {
    const float* inputs   = (const float*)d_in[0];
    const float* eig_vals = (const float*)d_in[1];
    const float* eig_vecs = (const float*)d_in[2];
    const float* w_filt   = (const float*)d_in[3];
    const float* w_inp    = (const float*)d_in[4];
    const float* ln1_s    = (const float*)d_in[5];
    const float* ln1_b    = (const float*)d_in[6];
    const float* wq       = (const float*)d_in[7];
    const float* wk       = (const float*)d_in[8];
    const float* wv       = (const float*)d_in[9];
    const float* wo       = (const float*)d_in[10];
    const float* ln2_s    = (const float*)d_in[11];
    const float* ln2_b    = (const float*)d_in[12];
    const float* w1       = (const float*)d_in[13];
    const float* b1       = (const float*)d_in[14];
    const float* w2       = (const float*)d_in[15];
    const float* b2       = (const float*)d_in[16];
    float* out = (float*)d_out;
    char* ws = (char*)d_ws;
    const size_t MB = 1u << 20;
    // Region plan (peak 192MB):
    //   0-16  : INb bf16                 [dead after XI gemm]
    //  16-42  : weights: WIt@16, WQKVt@18(6MB), WOt@24, W1t@26, W2t@34
    //  48-64  : XIH f16 [M,1024]         [dead after transpose]
    //  64-80  : XIT f16 [1024,M]         [dead after conv]
    //  48-112 : HID bf16 (MLP phase; XIH/XIT+STU dead by then)
    //  80-112 : STU fp32                 [dead after WO gemm]
    // 112-128 : XN bf16                  [dead after QKV gemm]
    // 128-176 : QKV bf16 fused [M,3072]  [dead after attn]
    // 128-160 : Xb fp32 (after attn)
    // 160-176 : YN bf16 (after WO gemm)
    // 176-180 : FvT f16 [1024,L]         [dead after conv]
    // 176-192 : Ab bf16 (after attn)     [dead after WO gemm]
    u16*   INb   = (u16*)(ws + 0 * MB);
    u16*   WIt   = (u16*)(ws + 16 * MB);
    u16*   WQKVt = (u16*)(ws + 18 * MB);
    u16*   WOt   = (u16*)(ws + 24 * MB);
    u16*   W1t   = (u16*)(ws + 26 * MB);
    u16*   W2t   = (u16*)(ws + 34 * MB);
    u16*   XIH   = (u16*)(ws + 48 * MB);
    u16*   HID   = (u16*)(ws + 48 * MB);
    u16*   XIT   = (u16*)(ws + 64 * MB);
    float* STU   = (float*)(ws + 80 * MB);
    u16*   XN    = (u16*)(ws + 112 * MB);
    u16*   QKV   = (u16*)(ws + 128 * MB);
    float* Xb    = (float*)(ws + 128 * MB);
    u16*   YN    = (u16*)(ws + 160 * MB);
    u16*   FvT   = (u16*)(ws + 176 * MB);
    u16*   Ab    = (u16*)(ws + 176 * MB);

    const int M = B_ * L_;

    cast_bf16<<<(M * D_ / 4 + 255) / 256, 256, 0, stream>>>(inputs, INb);
    cast_T<<<dim3(D_ / 32, D_ / 32), 256, 0, stream>>>(w_inp, WIt, D_, D_);
    cast_T<<<dim3(D_ / 32, D_ / 32), 256, 0, stream>>>(wq, WQKVt + 0 * D_ * D_, D_, D_);
    cast_T<<<dim3(D_ / 32, D_ / 32), 256, 0, stream>>>(wk, WQKVt + 1 * D_ * D_, D_, D_);
    cast_T<<<dim3(D_ / 32, D_ / 32), 256, 0, stream>>>(wv, WQKVt + 2 * D_ * D_, D_, D_);
    cast_T<<<dim3(D_ / 32, D_ / 32), 256, 0, stream>>>(wo, WOt, D_, D_);
    cast_T<<<dim3(MLP_ / 32, D_ / 32), 256, 0, stream>>>(w1, W1t, D_, MLP_);
    cast_T<<<dim3(D_ / 32, MLP_ / 32), 256, 0, stream>>>(w2, W2t, MLP_, D_);

    filters_T<<<dim3(L_ / 64, D_ / 64), 256, 0, stream>>>(eig_vals, eig_vecs, w_filt, FvT);

    // XI = INb @ WIt^T, written f16 [M][D], then transposed to [D][M]
    gemm_bf16<<<dim3(D_ / 128, M / 128), 256, 0, stream>>>(
        INb, WIt, nullptr, XIH, M, D_, D_, 1.f, nullptr, nullptr, 0, 0, 1);
    transpose_h<<<dim3(M / 64, D_ / 64), 256, 0, stream>>>(XIH, XIT);
    conv_k<<<dim3(16, D_ / 64, B_), 256, 0, stream>>>(FvT, XIT, STU);
    layernorm_bf16<<<M, 256, 0, stream>>>(STU, ln1_s, ln1_b, XN);
    // fused QKV (cols<1024 get the 1/sqrt(hd) Q-scale)
    gemm_bf16<<<dim3(3 * D_ / 128, M / 128), 256, 0, stream>>>(
        XN, WQKVt, nullptr, QKV, M, 3 * D_, D_, 1.f, nullptr, nullptr, 0, D_, 0);
    attn_mfma<<<dim3(L_ / 128, B_ * H_), 256, 0, stream>>>(
        QKV, QKV + D_, QKV + 2 * D_, Ab);
    gemm_bf16<<<dim3(D_ / 128, M / 128), 256, 0, stream>>>(
        Ab, WOt, Xb, nullptr, M, D_, D_, 1.f, nullptr, STU, 0, 0, 0);
    layernorm_bf16<<<M, 256, 0, stream>>>(Xb, ln2_s, ln2_b, YN);
    gemm_bf16<<<dim3(MLP_ / 128, M / 128), 256, 0, stream>>>(
        YN, W1t, nullptr, HID, M, MLP_, D_, 1.f, b1, nullptr, 1, 0, 0);
    gemm_bf16<<<dim3(D_ / 128, M / 128), 256, 0, stream>>>(
        HID, W2t, out, nullptr, M, D_, MLP_, 1.f, b2, Xb, 0, 0, 0);
}

// Round 6
// 824.403 us; speedup vs baseline: 1.2604x; 1.1712x over previous
//
#include <hip/hip_runtime.h>
#include <math.h>

#define B_ 4
#define L_ 2048
#define D_ 1024
#define H_ 16
#define HD_ 64
#define K_ 24
#define MLP_ 4096

typedef unsigned short u16;
typedef short s16x8 __attribute__((ext_vector_type(8)));
typedef float fx4 __attribute__((ext_vector_type(4)));
typedef _Float16 h2 __attribute__((ext_vector_type(2)));

__device__ __forceinline__ u16 f2bf(float f) {
    unsigned u = __float_as_uint(f);
    unsigned r = (u + 0x7fff + ((u >> 16) & 1)) >> 16;
    return (u16)r;
}

__device__ __forceinline__ u16 f2h(float f) {
    _Float16 hv = (_Float16)f;
    return __builtin_bit_cast(u16, hv);
}

__device__ __forceinline__ float gelu_t(float x) {
    float u = 0.7978845608028654f * (x + 0.044715f * x * x * x);
    return x / (1.f + __expf(-2.f * u));
}

__device__ __forceinline__ void gload_lds16(const void* g, void* l) {
    __builtin_amdgcn_global_load_lds(
        (const __attribute__((address_space(1))) unsigned int*)g,
        (__attribute__((address_space(3))) unsigned int*)l, 16, 0, 0);
}

#define SBAR() do { __builtin_amdgcn_sched_barrier(0); \
                    __builtin_amdgcn_s_barrier(); \
                    __builtin_amdgcn_sched_barrier(0); } while (0)

// ---------------------------------------------------------------------------
// Spectral filters, computed directly transposed+reversed:
// FvT[d][l0 + (l&63)^63] = sum_k eig_vecs[l,k]*ev^0.25[k]*w_filters[k,d] (f16)
// ---------------------------------------------------------------------------
__global__ __launch_bounds__(256) void filters_T(const float* __restrict__ eig_vals,
                                                 const float* __restrict__ eig_vecs,
                                                 const float* __restrict__ w_filters,
                                                 u16* __restrict__ outT) {
    int l0 = blockIdx.x * 64, d0 = blockIdx.y * 64;
    __shared__ float ev25[K_];
    __shared__ float rr[64][25];
    __shared__ float wfs[K_][64];
    int tid = threadIdx.x;
    if (tid < K_) ev25[tid] = powf(eig_vals[tid], 0.25f);
    __syncthreads();
    for (int i = tid; i < 64 * K_; i += 256)
        rr[i / K_][i % K_] = eig_vecs[l0 * K_ + i];
    for (int i = tid; i < K_ * 64; i += 256) {
        int k = i >> 6, dd = i & 63;
        wfs[k][dd] = ev25[k] * w_filters[k * D_ + d0 + dd];
    }
    __syncthreads();
    int lane = tid & 63, w = tid >> 6;
    float acc[16];
#pragma unroll
    for (int i = 0; i < 16; i++) acc[i] = 0.f;
#pragma unroll
    for (int k = 0; k < K_; k++) {
        float rv = rr[lane][k];
#pragma unroll
        for (int i = 0; i < 16; i++) acc[i] += rv * wfs[k][w * 16 + i];
    }
#pragma unroll
    for (int i = 0; i < 16; i++)
        outT[(size_t)(d0 + w * 16 + i) * L_ + l0 + (lane ^ 63)] = f2h(acc[i]);
}

// ---------------------------------------------------------------------------
// f16 [M][D] -> f16 [D][M] transpose (64x64 LDS tiles)
// ---------------------------------------------------------------------------
__global__ __launch_bounds__(256) void transpose_h(const u16* __restrict__ in,
                                                   u16* __restrict__ outT) {
    __shared__ u16 t[64][68];
    int m0 = blockIdx.x * 64, d0 = blockIdx.y * 64;
    int tid = threadIdx.x;
    int r = tid >> 3, c8 = (tid & 7) * 8;
#pragma unroll
    for (int p = 0; p < 2; p++) {
        uint4 X = *(const uint4*)&in[(size_t)(m0 + r + p * 32) * D_ + d0 + c8];
        *(uint2*)&t[r + p * 32][c8] = make_uint2(X.x, X.y);
        *(uint2*)&t[r + p * 32][c8 + 4] = make_uint2(X.z, X.w);
    }
    __syncthreads();
    int dr = tid >> 3, mc = (tid & 7) * 8;
#pragma unroll
    for (int p = 0; p < 2; p++) {
        int d = dr + p * 32;
        unsigned h[8];
#pragma unroll
        for (int j = 0; j < 8; j++) h[j] = t[mc + j][d];
        uint4 o;
        o.x = h[0] | (h[1] << 16); o.y = h[2] | (h[3] << 16);
        o.z = h[4] | (h[5] << 16); o.w = h[6] | (h[7] << 16);
        *(uint4*)&outT[(size_t)(d0 + d) * (size_t)(B_ * L_) + m0 + mc] = o;
    }
}

// ---------------------------------------------------------------------------
__global__ __launch_bounds__(256) void cast_bf16(const float* __restrict__ in,
                                                 u16* __restrict__ out) {
    int i = blockIdx.x * 256 + threadIdx.x;
    float4 v = ((const float4*)in)[i];
    ushort4 o;
    o.x = f2bf(v.x); o.y = f2bf(v.y); o.z = f2bf(v.z); o.w = f2bf(v.w);
    ((ushort4*)out)[i] = o;
}

// ---------------------------------------------------------------------------
// fp32 [R][C] -> bf16 [C][R] transpose-cast (32x32 LDS tile)
// ---------------------------------------------------------------------------
__global__ __launch_bounds__(256) void cast_T(const float* __restrict__ in,
                                              u16* __restrict__ out, int R, int C) {
    __shared__ float t[32][33];
    int c0 = blockIdx.x * 32, r0 = blockIdx.y * 32;
    int tx = threadIdx.x & 31, ty = threadIdx.x >> 5;
#pragma unroll
    for (int p = 0; p < 4; p++)
        t[ty + p * 8][tx] = in[(size_t)(r0 + ty + p * 8) * C + c0 + tx];
    __syncthreads();
#pragma unroll
    for (int p = 0; p < 4; p++)
        out[(size_t)(c0 + ty + p * 8) * R + r0 + tx] = f2bf(t[tx][ty + p * 8]);
}

// ---------------------------------------------------------------------------
// bf16 MFMA GEMM, 8-phase schedule (T2+T3+T4+T5 from the technique catalog).
// Tile 128x256, BK=64, 512 threads = 8 waves (2M x 4N), per-wave 64x64 C.
// 3-slot LDS rotation (48KB/tile): read slot(t), stage slot(t+2) [clamped so
// vmcnt counts stay exact at the tail], counted vmcnt(6) once per K-tile.
// st_16x32 swizzle: linear LDS dest (global_load_lds) + inverse-swizzled
// global source + swizzled ds_read (elem col ^16 when row bit2 set).
// Per K-tile: phase kk0 {12 ds_read_b128, 3 stage, bar, lgkm0, setprio,
// 16 MFMA, setprio, bar}; phase kk1 {4 ds_read, 3 stage, bar, lgkm0,
// setprio, 16 MFMA, setprio, vmcnt(6), bar}.
// Epilogue: out = act(alpha * A@Bt^T + bias) + resid; qcols Q-scale; f16out.
// ---------------------------------------------------------------------------
__global__ __launch_bounds__(512, 2) void gemm_bf16(
    const u16* __restrict__ A, const u16* __restrict__ Bt,
    float* __restrict__ C, u16* __restrict__ Cb,
    int M, int N, int K, float alpha,
    const float* __restrict__ bias, const float* __restrict__ resid, int act,
    int qcols, int f16out) {
    __shared__ __align__(16) u16 lds[3 * 24576];   // 3 slots x 48KB
    const int SLOT = 24576;   // u16 per slot
    const int BOFF = 8192;    // B-tile offset within slot (u16)

    int tid = threadIdx.x;
    int wid = tid >> 6, lane = tid & 63;
    int quad = lane >> 4, l15 = lane & 15;
    int rb = wid >> 2, cb = wid & 3;

    int bxs = blockIdx.x, bys = blockIdx.y;
    if ((gridDim.y & 7) == 0) {
        int bid = blockIdx.x + gridDim.x * blockIdx.y;
        int xcd = bid & 7, idx = bid >> 3;
        bys = xcd + 8 * (idx / gridDim.x);
        bxs = idx % gridDim.x;
    }
    int bm = bys * 128, bn = bxs * 256;
    int nt = K >> 6;

    // swizzled read bases (u16 units): row stride 64, elem-col ^16 if row&4
    int qoffe = (quad * 8) ^ ((l15 & 4) ? 16 : 0);
    int aRd = (rb * 64 + l15) * 64 + qoffe;            // + mf*1024 + kk*32
    int bRd = BOFF + (cb * 64 + l15) * 64 + qoffe;     // + nf*1024 + kk*32

    // staging: 64-row chunks, 8 rows/wave, lane>>3 row, (lane&7)*8 col ^16 hi
    int srow = wid * 8 + (lane >> 3);
    int scole = ((lane & 7) * 8) ^ ((lane & 32) ? 16 : 0);
    const u16* Ag = A + (size_t)(bm + srow) * K + scole;
    const u16* Bg = Bt + (size_t)(bn + srow) * K + scole;
    int ldst = wid * 512;   // wave-uniform dest offset within 4096-u16 chunk

#define STAGE_A(s, t, c) gload_lds16(Ag + (size_t)(c) * 64 * K + (size_t)(t) * 64, \
                                     &lds[(s) * SLOT + (c) * 4096 + ldst])
#define STAGE_B(s, t, c) gload_lds16(Bg + (size_t)(c) * 64 * K + (size_t)(t) * 64, \
                                     &lds[(s) * SLOT + BOFF + (c) * 4096 + ldst])

    // prologue: tile0 -> slot0, tile1 -> slot1; wait tile0, keep tile1 flying
    STAGE_A(0, 0, 0); STAGE_A(0, 0, 1);
    STAGE_B(0, 0, 0); STAGE_B(0, 0, 1); STAGE_B(0, 0, 2); STAGE_B(0, 0, 3);
    STAGE_A(1, 1, 0); STAGE_A(1, 1, 1);
    STAGE_B(1, 1, 0); STAGE_B(1, 1, 1); STAGE_B(1, 1, 2); STAGE_B(1, 1, 3);
    asm volatile("s_waitcnt vmcnt(6)" ::: "memory");
    SBAR();

    fx4 acc[4][4];
#pragma unroll
    for (int i = 0; i < 4; i++)
#pragma unroll
        for (int j = 0; j < 4; j++) acc[i][j] = (fx4){0.f, 0.f, 0.f, 0.f};

    int sa = 0, sb = 1, sc = 2;
    for (int t = 0; t < nt; t++) {
        int ts = (t + 2 < nt) ? t + 2 : nt - 1;
        const u16* ap = &lds[sa * SLOT + aRd];
        const u16* bp = &lds[sa * SLOT + bRd];
        s16x8 a[4], b[2][4];
        // ---------------- phase kk0 ----------------
#pragma unroll
        for (int mf = 0; mf < 4; mf++) a[mf] = *(const s16x8*)(ap + mf * 1024);
#pragma unroll
        for (int kk = 0; kk < 2; kk++)
#pragma unroll
            for (int nf = 0; nf < 4; nf++)
                b[kk][nf] = *(const s16x8*)(bp + nf * 1024 + kk * 32);
        STAGE_A(sc, ts, 0); STAGE_A(sc, ts, 1); STAGE_B(sc, ts, 0);
        SBAR();
        asm volatile("s_waitcnt lgkmcnt(0)" ::: "memory");
        __builtin_amdgcn_sched_barrier(0);
        __builtin_amdgcn_s_setprio(1);
#pragma unroll
        for (int nf = 0; nf < 4; nf++)
#pragma unroll
            for (int mf = 0; mf < 4; mf++)
                acc[mf][nf] = __builtin_amdgcn_mfma_f32_16x16x32_bf16(
                    a[mf], b[0][nf], acc[mf][nf], 0, 0, 0);
        __builtin_amdgcn_s_setprio(0);
        SBAR();
        // ---------------- phase kk1 ----------------
#pragma unroll
        for (int mf = 0; mf < 4; mf++)
            a[mf] = *(const s16x8*)(ap + mf * 1024 + 32);
        STAGE_B(sc, ts, 1); STAGE_B(sc, ts, 2); STAGE_B(sc, ts, 3);
        SBAR();
        asm volatile("s_waitcnt lgkmcnt(0)" ::: "memory");
        __builtin_amdgcn_sched_barrier(0);
        __builtin_amdgcn_s_setprio(1);
#pragma unroll
        for (int nf = 0; nf < 4; nf++)
#pragma unroll
            for (int mf = 0; mf < 4; mf++)
                acc[mf][nf] = __builtin_amdgcn_mfma_f32_16x16x32_bf16(
                    a[mf], b[1][nf], acc[mf][nf], 0, 0, 0);
        __builtin_amdgcn_s_setprio(0);
        asm volatile("s_waitcnt vmcnt(6)" ::: "memory");
        __builtin_amdgcn_sched_barrier(0);
        SBAR();
        int tmp = sa; sa = sb; sb = sc; sc = tmp;
    }
#undef STAGE_A
#undef STAGE_B

    // epilogue
#pragma unroll
    for (int mf = 0; mf < 4; mf++) {
        int row0 = bm + rb * 64 + mf * 16 + quad * 4;
#pragma unroll
        for (int nf = 0; nf < 4; nf++) {
            int col = bn + cb * 64 + nf * 16 + l15;
            float a2 = (col < qcols) ? alpha * 0.125f : alpha;
            float bv = bias ? bias[col] : 0.f;
#pragma unroll
            for (int reg = 0; reg < 4; reg++) {
                float v = a2 * acc[mf][nf][reg] + bv;
                if (act) v = gelu_t(v);
                size_t idx = (size_t)(row0 + reg) * N + col;
                if (resid) v += resid[idx];
                if (C) C[idx] = v;
                else Cb[idx] = f16out ? f2h(v) : f2bf(v);
            }
        }
    }
}

// ---------------------------------------------------------------------------
// Causal per-channel conv: out[b,l,d] = sum_{t=0..l} F[t,d]*XI[b,l-t,d]
// Transposed f16 inputs, b128 staging, fdot2 ring kernel, XCD-group swizzle.
// ---------------------------------------------------------------------------
__global__ __launch_bounds__(256, 6) void conv_k(const u16* __restrict__ FT,
                                                 const u16* __restrict__ XT,
                                                 float* __restrict__ OUT) {
    int bid = blockIdx.x + 16 * (blockIdx.y + 16 * blockIdx.z);
    int xcd = bid & 7, ix = bid >> 3;
    int group = xcd * 8 + (ix >> 4);
    int xblk = ix & 15;
    int d0 = (group & 15) * 64, b = group >> 4;

    __shared__ u16 xs[64][132];
    __shared__ u16 ftr[64][68];
    int tid = threadIdx.x;
    int dd = tid & 63;
    int jg = tid >> 6;
    int L0 = jg * 16;
    int frow = tid >> 3, fq = (tid & 7) * 8;
    int xrow = tid >> 4, xq = (tid & 15) * 8;
    const u16* fbase = FT + (size_t)(d0 + frow) * L_ + fq;
    const u16* xbase = XT + (size_t)(d0 + xrow) * (B_ * L_) + (size_t)b * L_ + xq;

#pragma unroll 1
    for (int half = 0; half < 2; half++) {
        int lt = half ? (31 - xblk) : xblk;
        int l0 = lt * 64;
        float acc[16];
#pragma unroll
        for (int i = 0; i < 16; i++) acc[i] = 0.f;

        for (int t0 = 0; t0 <= l0; t0 += 64) {
            int jb = l0 - t0 - 64;
#pragma unroll
            for (int p = 0; p < 2; p++) {
                uint4 Fq = *(const uint4*)(fbase + (size_t)p * 32 * L_ + t0);
                *(uint2*)&ftr[frow + p * 32][fq] = make_uint2(Fq.x, Fq.y);
                *(uint2*)&ftr[frow + p * 32][fq + 4] = make_uint2(Fq.z, Fq.w);
            }
            if (jb >= 0) {
#pragma unroll
                for (int p = 0; p < 4; p++) {
                    uint4 Xq = *(const uint4*)(xbase + (size_t)p * 16 * (B_ * L_) + jb);
                    *(uint2*)&xs[xrow + p * 16][xq] = make_uint2(Xq.x, Xq.y);
                    *(uint2*)&xs[xrow + p * 16][xq + 4] = make_uint2(Xq.z, Xq.w);
                }
            } else {
#pragma unroll
                for (int p = 0; p < 4; p++) {
                    uint4 Xq = make_uint4(0, 0, 0, 0);
                    if (xq >= 64)
                        Xq = *(const uint4*)(xbase + (size_t)p * 16 * (B_ * L_) - 64);
                    *(uint2*)&xs[xrow + p * 16][xq] = make_uint2(Xq.x, Xq.y);
                    *(uint2*)&xs[xrow + p * 16][xq + 4] = make_uint2(Xq.z, Xq.w);
                }
            }
            __syncthreads();

            unsigned Q[10], E[10];
            {
                uint2 q0 = *(const uint2*)&xs[dd][L0];
                uint2 q1 = *(const uint2*)&xs[dd][L0 + 4];
                uint2 q2 = *(const uint2*)&xs[dd][L0 + 8];
                uint2 q3 = *(const uint2*)&xs[dd][L0 + 12];
                Q[0] = q0.x; Q[1] = q0.y; Q[2] = q1.x; Q[3] = q1.y;
                Q[4] = q2.x; Q[5] = q2.y; Q[6] = q3.x; Q[7] = q3.y;
#pragma unroll
                for (int j = 0; j < 7; j++)
                    E[j] = __builtin_amdgcn_alignbit(Q[j + 1], Q[j], 16);
            }
#pragma unroll
            for (int s = 0; s < 16; s++) {
                const int h = (2 * s) % 10;
                uint2 nx = *(const uint2*)&xs[dd][L0 + 16 + 4 * s];
                Q[(h + 8) % 10] = nx.x;
                Q[(h + 9) % 10] = nx.y;
                E[(h + 7) % 10] = __builtin_amdgcn_alignbit(Q[(h + 8) % 10], Q[(h + 7) % 10], 16);
                E[(h + 8) % 10] = __builtin_amdgcn_alignbit(Q[(h + 9) % 10], Q[(h + 8) % 10], 16);
                uint2 fr = *(const uint2*)&ftr[dd][4 * s];
                h2 f01 = __builtin_bit_cast(h2, fr.x);
                h2 f23 = __builtin_bit_cast(h2, fr.y);
#pragma unroll
                for (int i = 0; i < 16; i += 2) {
                    const int p = (h + i / 2) % 10;
                    const int p1 = (h + i / 2 + 1) % 10;
                    const int p2 = (h + i / 2 + 2) % 10;
                    acc[i] = __builtin_amdgcn_fdot2(f01, __builtin_bit_cast(h2, E[p]), acc[i], false);
                    acc[i] = __builtin_amdgcn_fdot2(f23, __builtin_bit_cast(h2, E[p1]), acc[i], false);
                    acc[i + 1] = __builtin_amdgcn_fdot2(f01, __builtin_bit_cast(h2, Q[p1]), acc[i + 1], false);
                    acc[i + 1] = __builtin_amdgcn_fdot2(f23, __builtin_bit_cast(h2, Q[p2]), acc[i + 1], false);
                }
            }
            __syncthreads();
        }
#pragma unroll
        for (int i = 0; i < 16; i++)
            OUT[((size_t)b * L_ + l0 + L0 + i) * D_ + d0 + dd] = acc[i];
    }
}

// ---------------------------------------------------------------------------
// LayerNorm -> bf16 out (row = 1024), eps 1e-6
// ---------------------------------------------------------------------------
__global__ __launch_bounds__(256) void layernorm_bf16(const float* __restrict__ x,
                                                      const float* __restrict__ scale,
                                                      const float* __restrict__ bias,
                                                      u16* __restrict__ y) {
    size_t row = blockIdx.x;
    int tid = threadIdx.x;
    const float4 v = *(const float4*)&x[row * D_ + tid * 4];
    float s = v.x + v.y + v.z + v.w;
    float q = v.x * v.x + v.y * v.y + v.z * v.z + v.w * v.w;
#pragma unroll
    for (int off = 32; off >= 1; off >>= 1) {
        s += __shfl_xor(s, off, 64);
        q += __shfl_xor(q, off, 64);
    }
    __shared__ float ss[4], sq[4];
    int w = tid >> 6;
    if ((tid & 63) == 0) { ss[w] = s; sq[w] = q; }
    __syncthreads();
    s = ss[0] + ss[1] + ss[2] + ss[3];
    q = sq[0] + sq[1] + sq[2] + sq[3];
    float mean = s * (1.f / D_);
    float var = q * (1.f / D_) - mean * mean;
    float r = rsqrtf(var + 1e-6f);
    const float4 sc = *(const float4*)&scale[tid * 4];
    const float4 bi = *(const float4*)&bias[tid * 4];
    ushort4 o;
    o.x = f2bf((v.x - mean) * r * sc.x + bi.x);
    o.y = f2bf((v.y - mean) * r * sc.y + bi.y);
    o.z = f2bf((v.z - mean) * r * sc.z + bi.z);
    o.w = f2bf((v.w - mean) * r * sc.w + bi.w);
    *(ushort4*)&y[row * D_ + tid * 4] = o;
}

// ---------------------------------------------------------------------------
// MFMA flash attention, TQ=128. no-max softmax + K/V reg prefetch + XCD swz.
// ---------------------------------------------------------------------------
__global__ __launch_bounds__(256) void attn_mfma(const u16* __restrict__ Qg,
                                                 const u16* __restrict__ Kg,
                                                 const u16* __restrict__ Vg,
                                                 u16* __restrict__ Og) {
    const int QSTR = 3072;
    int bxs = blockIdx.x, bys = blockIdx.y;
    {
        int bid = blockIdx.x + gridDim.x * blockIdx.y;
        int xcd = bid & 7, idx = bid >> 3;
        bys = xcd + 8 * (idx / gridDim.x);
        bxs = idx % gridDim.x;
    }
    int q0 = bxs * 128;
    int b = bys >> 4, h = bys & 15;
    __shared__ __align__(16) u16 qs[128 * 72];
    __shared__ __align__(16) u16 ks[64 * 72];
    __shared__ __align__(16) u16 vt[64 * 72];   // V^T: [hd][s]
    int tid = threadIdx.x;
    int w = tid >> 6, lane = tid & 63;
    int quad = lane >> 4, l15 = lane & 15;
    const size_t base = (size_t)b * L_ * QSTR + h * HD_;

#pragma unroll
    for (int i = tid; i < 128 * 8; i += 256) {
        int r = i >> 3, c = i & 7;
        *(uint4*)&qs[r * 72 + c * 8] =
            *(const uint4*)&Qg[base + (size_t)(q0 + r) * QSTR + c * 8];
    }
    __syncthreads();
    s16x8 aq[2][2];
#pragma unroll
    for (int mi = 0; mi < 2; mi++)
#pragma unroll
        for (int kb = 0; kb < 2; kb++)
            aq[mi][kb] = *(const s16x8*)&qs[(w * 32 + mi * 16 + l15) * 72 + kb * 32 + quad * 8];

    float rsacc[2][4];
    fx4 o[2][4];
#pragma unroll
    for (int mi = 0; mi < 2; mi++)
#pragma unroll
        for (int i = 0; i < 4; i++) {
            rsacc[mi][i] = 0.f;
            o[mi][i] = (fx4){0.f, 0.f, 0.f, 0.f};
        }
    u16* psw = qs + w * 32 * 72;

    int kr0 = tid >> 3, kc = tid & 7;
    const u16* kg0 = Kg + base + (size_t)kr0 * QSTR + kc * 8;
    const u16* kg1 = kg0 + (size_t)32 * QSTR;
    const u16* vg = Vg + base + (size_t)lane * QSTR + w * 8;
    uint4 kp0 = *(const uint4*)kg0;
    uint4 kp1 = *(const uint4*)kg1;
    uint4 vp0 = *(const uint4*)vg;
    uint4 vp1 = *(const uint4*)(vg + 32);

    for (int s0 = 0; s0 < L_; s0 += 64) {
        __syncthreads();
        *(uint4*)&ks[kr0 * 72 + kc * 8] = kp0;
        *(uint4*)&ks[(kr0 + 32) * 72 + kc * 8] = kp1;
        {
            u16 t0[8], t1[8];
            *(uint4*)t0 = vp0;
            *(uint4*)t1 = vp1;
#pragma unroll
            for (int j = 0; j < 8; j++) vt[(w * 8 + j) * 72 + lane] = t0[j];
#pragma unroll
            for (int j = 0; j < 8; j++) vt[(w * 8 + 32 + j) * 72 + lane] = t1[j];
        }
        if (s0 + 64 < L_) {
            size_t off = (size_t)(s0 + 64) * QSTR;
            kp0 = *(const uint4*)(kg0 + off);
            kp1 = *(const uint4*)(kg1 + off);
            vp0 = *(const uint4*)(vg + off);
            vp1 = *(const uint4*)(vg + off + 32);
        }
        __syncthreads();

        fx4 sv[2][4];
#pragma unroll
        for (int mi = 0; mi < 2; mi++)
#pragma unroll
            for (int nt = 0; nt < 4; nt++) sv[mi][nt] = (fx4){0.f, 0.f, 0.f, 0.f};
#pragma unroll
        for (int kb = 0; kb < 2; kb++)
#pragma unroll
            for (int nt = 0; nt < 4; nt++) {
                s16x8 bk = *(const s16x8*)&ks[(nt * 16 + l15) * 72 + kb * 32 + quad * 8];
#pragma unroll
                for (int mi = 0; mi < 2; mi++)
                    sv[mi][nt] = __builtin_amdgcn_mfma_f32_16x16x32_bf16(
                        aq[mi][kb], bk, sv[mi][nt], 0, 0, 0);
            }

#pragma unroll
        for (int mi = 0; mi < 2; mi++)
#pragma unroll
            for (int nt = 0; nt < 4; nt++)
#pragma unroll
                for (int reg = 0; reg < 4; reg++) {
                    float p = __expf(sv[mi][nt][reg]);
                    rsacc[mi][reg] += p;
                    psw[(mi * 16 + quad * 4 + reg) * 72 + nt * 16 + l15] = f2bf(p);
                }

#pragma unroll
        for (int kb = 0; kb < 2; kb++) {
            s16x8 ap[2];
#pragma unroll
            for (int mi = 0; mi < 2; mi++)
                ap[mi] = *(const s16x8*)&psw[(mi * 16 + l15) * 72 + kb * 32 + quad * 8];
#pragma unroll
            for (int nt = 0; nt < 4; nt++) {
                s16x8 bv = *(const s16x8*)&vt[(nt * 16 + l15) * 72 + kb * 32 + quad * 8];
#pragma unroll
                for (int mi = 0; mi < 2; mi++)
                    o[mi][nt] = __builtin_amdgcn_mfma_f32_16x16x32_bf16(
                        ap[mi], bv, o[mi][nt], 0, 0, 0);
            }
        }
    }
    float lsum[2][4];
#pragma unroll
    for (int mi = 0; mi < 2; mi++)
#pragma unroll
        for (int reg = 0; reg < 4; reg++) {
            float r = rsacc[mi][reg];
#pragma unroll
            for (int off = 8; off >= 1; off >>= 1)
                r += __shfl_xor(r, off, 16);
            lsum[mi][reg] = r;
        }
    const size_t baseo = (size_t)b * L_ * 1024 + h * HD_;
#pragma unroll
    for (int mi = 0; mi < 2; mi++)
#pragma unroll
        for (int reg = 0; reg < 4; reg++) {
            float inv = 1.f / lsum[mi][reg];
            size_t row = baseo +
                (size_t)(q0 + w * 32 + mi * 16 + quad * 4 + reg) * 1024;
#pragma unroll
            for (int nt = 0; nt < 4; nt++)
                Og[row + nt * 16 + l15] = f2bf(o[mi][nt][reg] * inv);
        }
}

// ---------------------------------------------------------------------------
extern "C" void kernel_launch(void* const* d_in, const int* in_sizes, int n_in,
                              void* d_out, int out_size, void* d_ws, size_t ws_size,
                              hipStream_t stream) {
    const float* inputs   = (const float*)d_in[0];
    const float* eig_vals = (const float*)d_in[1];
    const float* eig_vecs = (const float*)d_in[2];
    const float* w_filt   = (const float*)d_in[3];
    const float* w_inp    = (const float*)d_in[4];
    const float* ln1_s    = (const float*)d_in[5];
    const float* ln1_b    = (const float*)d_in[6];
    const float* wq       = (const float*)d_in[7];
    const float* wk       = (const float*)d_in[8];
    const float* wv       = (const float*)d_in[9];
    const float* wo       = (const float*)d_in[10];
    const float* ln2_s    = (const float*)d_in[11];
    const float* ln2_b    = (const float*)d_in[12];
    const float* w1       = (const float*)d_in[13];
    const float* b1       = (const float*)d_in[14];
    const float* w2       = (const float*)d_in[15];
    const float* b2       = (const float*)d_in[16];
    float* out = (float*)d_out;
    char* ws = (char*)d_ws;
    const size_t MB = 1u << 20;
    u16*   INb   = (u16*)(ws + 0 * MB);
    u16*   WIt   = (u16*)(ws + 16 * MB);
    u16*   WQKVt = (u16*)(ws + 18 * MB);
    u16*   WOt   = (u16*)(ws + 24 * MB);
    u16*   W1t   = (u16*)(ws + 26 * MB);
    u16*   W2t   = (u16*)(ws + 34 * MB);
    u16*   XIH   = (u16*)(ws + 48 * MB);
    u16*   HID   = (u16*)(ws + 48 * MB);
    u16*   XIT   = (u16*)(ws + 64 * MB);
    float* STU   = (float*)(ws + 80 * MB);
    u16*   XN    = (u16*)(ws + 112 * MB);
    u16*   QKV   = (u16*)(ws + 128 * MB);
    float* Xb    = (float*)(ws + 128 * MB);
    u16*   YN    = (u16*)(ws + 160 * MB);
    u16*   FvT   = (u16*)(ws + 176 * MB);
    u16*   Ab    = (u16*)(ws + 176 * MB);

    const int M = B_ * L_;

    cast_bf16<<<(M * D_ / 4 + 255) / 256, 256, 0, stream>>>(inputs, INb);
    cast_T<<<dim3(D_ / 32, D_ / 32), 256, 0, stream>>>(w_inp, WIt, D_, D_);
    cast_T<<<dim3(D_ / 32, D_ / 32), 256, 0, stream>>>(wq, WQKVt + 0 * D_ * D_, D_, D_);
    cast_T<<<dim3(D_ / 32, D_ / 32), 256, 0, stream>>>(wk, WQKVt + 1 * D_ * D_, D_, D_);
    cast_T<<<dim3(D_ / 32, D_ / 32), 256, 0, stream>>>(wv, WQKVt + 2 * D_ * D_, D_, D_);
    cast_T<<<dim3(D_ / 32, D_ / 32), 256, 0, stream>>>(wo, WOt, D_, D_);
    cast_T<<<dim3(MLP_ / 32, D_ / 32), 256, 0, stream>>>(w1, W1t, D_, MLP_);
    cast_T<<<dim3(D_ / 32, MLP_ / 32), 256, 0, stream>>>(w2, W2t, MLP_, D_);

    filters_T<<<dim3(L_ / 64, D_ / 64), 256, 0, stream>>>(eig_vals, eig_vecs, w_filt, FvT);

    // XI = INb @ WIt^T -> f16 [M][D], then transpose to [D][M]
    gemm_bf16<<<dim3(D_ / 256, M / 128), 512, 0, stream>>>(
        INb, WIt, nullptr, XIH, M, D_, D_, 1.f, nullptr, nullptr, 0, 0, 1);
    transpose_h<<<dim3(M / 64, D_ / 64), 256, 0, stream>>>(XIH, XIT);
    conv_k<<<dim3(16, D_ / 64, B_), 256, 0, stream>>>(FvT, XIT, STU);
    layernorm_bf16<<<M, 256, 0, stream>>>(STU, ln1_s, ln1_b, XN);
    // fused QKV (cols<1024 get the 1/sqrt(hd) Q-scale)
    gemm_bf16<<<dim3(3 * D_ / 256, M / 128), 512, 0, stream>>>(
        XN, WQKVt, nullptr, QKV, M, 3 * D_, D_, 1.f, nullptr, nullptr, 0, D_, 0);
    attn_mfma<<<dim3(L_ / 128, B_ * H_), 256, 0, stream>>>(
        QKV, QKV + D_, QKV + 2 * D_, Ab);
    gemm_bf16<<<dim3(D_ / 256, M / 128), 512, 0, stream>>>(
        Ab, WOt, Xb, nullptr, M, D_, D_, 1.f, nullptr, STU, 0, 0, 0);
    layernorm_bf16<<<M, 256, 0, stream>>>(Xb, ln2_s, ln2_b, YN);
    gemm_bf16<<<dim3(MLP_ / 256, M / 128), 512, 0, stream>>>(
        YN, W1t, nullptr, HID, M, MLP_, D_, 1.f, b1, nullptr, 1, 0, 0);
    gemm_bf16<<<dim3(D_ / 256, M / 128), 512, 0, stream>>>(
        HID, W2t, out, nullptr, M, D_, MLP_, 1.f, b2, Xb, 0, 0, 0);
}